// Round 10
// baseline (4965.904 us; speedup 1.0000x reference)
//
#include <hip/hip_runtime.h>
#include <hip/hip_bf16.h>
#include <stdint.h>

typedef __hip_bfloat16 bf16;
typedef unsigned long long u64;
typedef short bf16x8 __attribute__((ext_vector_type(8)));
typedef float f32x4 __attribute__((ext_vector_type(4)));
#define DEVI static __device__ __forceinline__

DEVI float b2f(bf16 v){ return __bfloat162float(v); }
DEVI bf16  f2b(float v){ return __float2bfloat16(v); }
DEVI float bfL(unsigned u){ return __uint_as_float(u<<16); }
DEVI float bfH(unsigned u){ return __uint_as_float(u & 0xffff0000u); }
DEVI void unpack8(uint4 r, float* v){
  v[0]=bfL(r.x); v[1]=bfH(r.x); v[2]=bfL(r.y); v[3]=bfH(r.y);
  v[4]=bfL(r.z); v[5]=bfH(r.z); v[6]=bfL(r.w); v[7]=bfH(r.w);
}
DEVI void unpack4(uint2 r, float* v){
  v[0]=bfL(r.x); v[1]=bfH(r.x); v[2]=bfL(r.y); v[3]=bfH(r.y);
}
DEVI unsigned short bfr(float x){ bf16 h=f2b(x); return *reinterpret_cast<unsigned short*>(&h); }
DEVI unsigned pk2(float a,float b){ return (unsigned)bfr(a) | ((unsigned)bfr(b)<<16); }

constexpr int B_=4, N0=8192, M0=2048, M1=512, KK=32;
constexpr int L0=M0*KK, L1=M1*KK;       // 65536, 16384
constexpr int C0=192, H0=48, C1=384, H1=96;

// ---- output element offsets (FLOAT32), return order: p,cp1,cp2,f,f1,f2 ----
constexpr size_t OUT_P=0, OUT_CP1=98304, OUT_CP2=122880, OUT_F=129024,
                 OUT_F1=227328, OUT_F2=1800192;

// ---- workspace byte offsets ----
constexpr size_t A_FLAG  = 0;
constexpr size_t A_CP1F  = 256;
constexpr size_t A_CP2F  = A_CP1F+98304;
constexpr size_t A_IDX0  = A_CP2F+24576;
constexpr size_t A_IDX1  = A_IDX0+32768;
constexpr size_t A_GID0  = A_IDX1+8192;
constexpr size_t A_GID1  = A_GID0+1048576;
constexpr size_t A_FEAT0 = A_GID1+262144;          // bf16 B*6*L0 = 3145728
constexpr size_t A_M1V   = A_FEAT0+3145728;
constexpr size_t A_RS1V  = A_M1V+3072;
constexpr size_t A_SS01  = A_RS1V+3072;
constexpr size_t A_G1V   = A_SS01+3072;
constexpr size_t A_SUMA  = A_G1V+3072;             // 6144 (atomic, memset; fallback only)
constexpr size_t A_SS02  = A_SUMA+6144;            // 3072
constexpr size_t A_M2V   = A_SS02+3072;
constexpr size_t A_RS2V  = A_M2V+3072;
constexpr size_t A_G2V   = A_RS2V+3072;
constexpr size_t A_RAWP  = A_G2V+3072;             // f32 B*C0*M0 = 6291456
constexpr size_t A_RAWM2 = A_RAWP+6291456;         // f32 B*C0*M0 (becomes f1f)
constexpr size_t A_FEAT1 = A_RAWM2+6291456;        // = 17234176
// ---- y2 store (stage-0 only; overlaps stage-1 regions temporally) ----
constexpr size_t A_Y2    = A_FEAT1;                // bf16 B*C0*L0 = 100663296
constexpr size_t WS_Y2   = A_Y2 + 100663296;       // 117,897,472
// ---- stage-1 serial-mode buffers ----
constexpr size_t A_YB1   = A_FEAT1+6389760;
constexpr size_t A_YB2   = A_YB1+12582912;
constexpr size_t A_PMS1  = A_YB2+12582912;
constexpr size_t A_MS1   = A_PMS1+786432;
constexpr size_t A_RSS1  = A_MS1+1536;
constexpr size_t A_SSS1  = A_RSS1+1536;
constexpr size_t A_G1S1  = A_SSS1+1536;
constexpr size_t A_G2S1  = A_G1S1+1536;
// ---- stage-1 parallel-mode buffers ----
constexpr size_t A_F1A  = A_FEAT1;                 // bf16 B*195*L1 = 25559040
constexpr size_t A_YB1A = A_F1A + 25559040;
constexpr size_t A_YB2A = A_YB1A + 50331648;
constexpr size_t A_PMA  = A_YB2A + 50331648;
constexpr size_t A_MSA  = A_PMA + 3145728;
constexpr size_t A_RSA  = A_MSA + 6144;
constexpr size_t A_SSA  = A_RSA + 6144;
constexpr size_t A_G1A  = A_SSA + 6144;
constexpr size_t A_G2A  = A_G1A + 6144;
constexpr size_t A_NEED = A_G2A + 6144;            // 146,632,960
// ---- split bf16 weights for stage-1 MFMA convs (hi/lo) ----
constexpr size_t A_W1H  = A_NEED;                  // bf16 384*224 = 172032 B
constexpr size_t A_W1L  = A_W1H + 172032;
constexpr size_t A_W2H  = A_W1L + 172032;          // bf16 384*768 = 589824 B
constexpr size_t A_W2L  = A_W2H + 589824;
constexpr size_t A_NEED2= A_W2L + 589824;          // ~148.1 MB

DEVI const float* pick(const float* c0, const float* c1, const int* fl, int want_f){
  int sw = fl ? ((*fl)!=0) : 0;
  return (sw ^ want_f) ? c1 : c0;
}

__global__ __launch_bounds__(64)
void detect_kernel(const float* __restrict__ c0, int* __restrict__ flag){
  unsigned long long m = __ballot(c0[threadIdx.x] < 0.f);
  if(threadIdx.x==0) *flag = (m!=0ull) ? 1 : 0;
}

__global__ __launch_bounds__(256)
void cvt_pf_kernel(const float* __restrict__ c0, const float* __restrict__ c1,
                   const int* __restrict__ fl, float* __restrict__ outP,
                   float* __restrict__ outF, int n){
  const float* p = pick(c0,c1,fl,0);
  const float* f = pick(c0,c1,fl,1);
  int i=blockIdx.x*256+threadIdx.x;
  if(i<n){ outP[i]=p[i]; outF[i]=f[i]; }
}

// ---------------- FPS: no global traffic in the serial loop ----------------
// DPP wave-argmax carries (key, idx, x, y, z); winner coords published via LDS.
// Selections buffered in LDS (msel), written to global once at kernel end.
#define DPP_ARGMAX5(CTRL) { \
  int iv_=__builtin_amdgcn_update_dpp(__float_as_int(bv), __float_as_int(bv), CTRL, 0xF, 0xF, false); \
  int ii_=__builtin_amdgcn_update_dpp(bi, bi, CTRL, 0xF, 0xF, false); \
  int ix_=__builtin_amdgcn_update_dpp(__float_as_int(bx), __float_as_int(bx), CTRL, 0xF, 0xF, false); \
  int iy_=__builtin_amdgcn_update_dpp(__float_as_int(by), __float_as_int(by), CTRL, 0xF, 0xF, false); \
  int iz_=__builtin_amdgcn_update_dpp(__float_as_int(bz), __float_as_int(bz), CTRL, 0xF, 0xF, false); \
  float fv_=__int_as_float(iv_); \
  if(fv_>bv || (fv_==bv && ii_<bi)){ bv=fv_; bi=ii_; \
    bx=__int_as_float(ix_); by=__int_as_float(iy_); bz=__int_as_float(iz_); } }

template<int NP, int MS, int TPB>
__global__ __launch_bounds__(TPB)
void fps_kernel(const float* __restrict__ c0, const float* __restrict__ c1,
                const int* __restrict__ fl, int* __restrict__ sel){
  constexpr int CH = NP/TPB;
  constexpr int NW = TPB/64;
  __shared__ u64 kky[2][NW];
  __shared__ float4 kxy[2][NW];
  __shared__ int msel[MS];
  const float* pC = pick(c0,c1,fl,0);
  int b=blockIdx.x, t=threadIdx.x;
  const float* pb = pC + (size_t)b*NP*3;
  float ox[CH], oy[CH], oz[CH], dd[CH];
  #pragma unroll
  for(int c=0;c<CH;c++){
    int i=t*CH+c;
    ox[c]=pb[i*3]; oy[c]=pb[i*3+1]; oz[c]=pb[i*3+2];
    dd[c]=1e10f;
  }
  if(t==0) msel[0]=0;
  float cx=pb[0], cy=pb[1], cz=pb[2];   // broadcast global reads (exact f32)
  int par=0;
  for(int s=1;s<MS;s++){
    float bv=-1.f, bx=0.f, by=0.f, bz=0.f; int bi=0;
    #pragma unroll
    for(int c=0;c<CH;c++){
      float dx=__fsub_rn(ox[c],cx), dy=__fsub_rn(oy[c],cy), dz=__fsub_rn(oz[c],cz);
      float d=__fadd_rn(__fadd_rn(__fmul_rn(dx,dx),__fmul_rn(dy,dy)),__fmul_rn(dz,dz));
      float nd=fminf(dd[c],d); dd[c]=nd;
      if(nd>bv){ bv=nd; bi=t*CH+c; bx=ox[c]; by=oy[c]; bz=oz[c]; }  // strict >: first idx wins
    }
    DPP_ARGMAX5(0x111) DPP_ARGMAX5(0x112) DPP_ARGMAX5(0x114) DPP_ARGMAX5(0x118)
    DPP_ARGMAX5(0x142) DPP_ARGMAX5(0x143)
    if((t&63)==63){
      kky[par][t>>6] = (((u64)__float_as_uint(bv))<<32) | (unsigned)(0xFFFFFFFFu-(unsigned)bi);
      kxy[par][t>>6] = make_float4(bx,by,bz,0.f);
    }
    __syncthreads();
    u64 best=kky[par][0]; int kb=0;
    #pragma unroll
    for(int k=1;k<NW;k++){ u64 w=kky[par][k]; if(w>best){ best=w; kb=k; } }
    if(t==0) msel[s]=(int)(0xFFFFFFFFu-(unsigned)best);
    float4 c4=kxy[par][kb];               // winner coords, exact f32 register copies
    cx=c4.x; cy=c4.y; cz=c4.z;
    par^=1;
  }
  __syncthreads();
  for(int i=t;i<MS;i+=TPB) sel[(size_t)b*MS+i]=msel[i];
}

__global__ __launch_bounds__(256)
void gather_cp_kernel(const float* __restrict__ c0, const float* __restrict__ c1,
                      const int* __restrict__ fl, const int* __restrict__ sel,
                      int NP, int MS, float* __restrict__ cpf, float* __restrict__ outcp){
  const float* pC = pick(c0,c1,fl,0);
  int t=blockIdx.x*256+threadIdx.x;
  if(t>=B_*MS) return;
  int b=t/MS;
  int j=sel[t];
  const float* src=pC + ((size_t)b*NP + j)*3;
  float x=src[0],y=src[1],z=src[2];
  float* d=cpf + (size_t)t*3; d[0]=x; d[1]=y; d[2]=z;
  float* o=outcp + (size_t)t*3; o[0]=x; o[1]=y; o[2]=z;
}

// ---------------- ball query ----------------
template<int NP, int MS>
__global__ __launch_bounds__(256)
void ballq_kernel(const float* __restrict__ c0, const float* __restrict__ c1,
                  const int* __restrict__ fl, const float* __restrict__ cpf,
                  int* __restrict__ gidx){
  __shared__ int cand[4][64][33];
  __shared__ int ccnt[4][64];
  const float* pC = pick(c0,c1,fl,0);
  int t=threadIdx.x, q=t>>6, cl=t&63;
  int b=blockIdx.y, m=blockIdx.x*64+cl;
  const float* cc=cpf + ((size_t)b*MS+m)*3;
  float cx=cc[0], cy=cc[1], cz=cc[2];
  const float R2=0.01f;
  const float* pb=pC + (size_t)b*NP*3;
  int cnt=0;
  int j0=q*(NP/4), j1=j0+NP/4;
  for(int j=j0;j<j1;j++){
    if(cnt>=32) break;
    float dx=__fsub_rn(cx,pb[(size_t)j*3]);
    float dy=__fsub_rn(cy,pb[(size_t)j*3+1]);
    float dz=__fsub_rn(cz,pb[(size_t)j*3+2]);
    float d2=__fadd_rn(__fadd_rn(__fmul_rn(dx,dx),__fmul_rn(dy,dy)),__fmul_rn(dz,dz));
    if(d2<R2) cand[q][cl][cnt++]=j;
  }
  ccnt[q][cl]=cnt;
  __syncthreads();
  if(q==0){
    int* gp=gidx + ((size_t)b*MS+m)*32;
    int total=0, first=0; bool has=false;
    for(int qq=0;qq<4;qq++){
      int n=ccnt[qq][cl];
      for(int u=0;u<n;u++){
        if(total>=32) break;
        int id=cand[qq][cl][u];
        if(!has){ first=id; has=true; }
        gp[total++]=id;
      }
      if(total>=32) break;
    }
    if(!has){ for(int u=0;u<32;u++) gp[u]=0; }
    else    { for(int u=total;u<32;u++) gp[u]=first; }
  }
}

__global__ __launch_bounds__(256)
void feat0_kernel(const float* __restrict__ c0, const float* __restrict__ c1,
                  const int* __restrict__ fl, const float* __restrict__ cp1f,
                  const int* __restrict__ idx0, const int* __restrict__ gidx0,
                  bf16* __restrict__ feat){
  const float* p0f = pick(c0,c1,fl,0);
  const float* f_in= pick(c0,c1,fl,1);
  int t=blockIdx.x*256+threadIdx.x;
  int b=t>>16, rem=t&65535, m=rem>>5;
  int j=gidx0[t];
  int sel=idx0[(b<<11)+m];
  const float* pj=p0f + ((size_t)(b*N0)+j)*3;
  const float* cm=cp1f + ((size_t)(b*M0)+m)*3;
  bf16* fb=feat + (size_t)b*6*L0 + rem;
  fb[0]      =f2b(pj[0]-cm[0]);
  fb[L0]     =f2b(pj[1]-cm[1]);
  fb[2*L0]   =f2b(pj[2]-cm[2]);
  const float* fI=f_in + (size_t)b*3*N0;
  #pragma unroll
  for(int c=0;c<3;c++)
    fb[(size_t)(3+c)*L0]=f2b(fI[c*N0+j]-fI[c*N0+sel]);
}

// ---------------- stage-0 conv1 stats (I=6) ----------------
__global__ __launch_bounds__(256)
void s0c1_stats_kernel(const bf16* __restrict__ feat, const float* __restrict__ W1,
                       float* __restrict__ m1v, float* __restrict__ rs1v){
  int row=blockIdx.x, b=row/C0, c=row%C0, t=threadIdx.x;
  float w6[6];
  #pragma unroll
  for(int j=0;j<6;j++) w6[j]=W1[c*6+j];
  const bf16* fb=feat + (size_t)b*6*L0;
  float s=0.f,s2=0.f;
  for(int base=t*8;base<L0;base+=2048){
    float X[6][8];
    #pragma unroll
    for(int i=0;i<6;i++){ uint4 r=*(const uint4*)(fb+(size_t)i*L0+base); unpack8(r,X[i]); }
    #pragma unroll
    for(int u=0;u<8;u++){
      float y=0.f;
      #pragma unroll
      for(int j=0;j<6;j++) y=fmaf(w6[j],X[j][u],y);
      s+=y; s2+=y*y;
    }
  }
  #pragma unroll
  for(int off=32;off>0;off>>=1){ s+=__shfl_down(s,off,64); s2+=__shfl_down(s2,off,64); }
  __shared__ float as[4], bs[4];
  int w=t>>6;
  if((t&63)==0){ as[w]=s; bs[w]=s2; }
  __syncthreads();
  if(t==0){
    float S=as[0]+as[1]+as[2]+as[3], S2=bs[0]+bs[1]+bs[2]+bs[3];
    float m=S/(float)L0, var=S2/(float)L0-m*m;
    var=fmaxf(var,0.f);
    m1v[row]=m; rs1v[row]=rsqrtf(var+1e-5f);
  }
}

// ---------------- stage-0 pool: ssum + raw k-max (g1 factored out) ----------------
__global__ __launch_bounds__(256)
void s0c1_pool_kernel(const bf16* __restrict__ feat, const float* __restrict__ W1,
                      const float* __restrict__ m1v, const float* __restrict__ rs1v,
                      float* __restrict__ rawp, float* __restrict__ ss01){
  int row=blockIdx.x, b=row/C0, c=row%C0, t=threadIdx.x;
  float w6[6];
  #pragma unroll
  for(int j=0;j<6;j++) w6[j]=W1[c*6+j];
  const bf16* fb=feat + (size_t)b*6*L0;
  float m=m1v[row], rs=rs1v[row];
  float ss=0.f;
  for(int base=t*8;base<L0;base+=2048){
    float X[6][8];
    #pragma unroll
    for(int i=0;i<6;i++){ uint4 r=*(const uint4*)(fb+(size_t)i*L0+base); unpack8(r,X[i]); }
    float mx=-3e38f;
    #pragma unroll
    for(int u=0;u<8;u++){
      float y=0.f;
      #pragma unroll
      for(int j=0;j<6;j++) y=fmaf(w6[j],X[j][u],y);
      float x=fmaxf((y-m)*rs,0.f);
      ss+=x; mx=fmaxf(mx,x);
    }
    mx=fmaxf(mx,__shfl_down(mx,2,64));
    mx=fmaxf(mx,__shfl_down(mx,1,64));
    if((t&3)==0) rawp[(size_t)row*M0 + (base>>5)] = mx;
  }
  #pragma unroll
  for(int off=32;off>0;off>>=1) ss+=__shfl_down(ss,off,64);
  __shared__ float as[4];
  int w=t>>6;
  if((t&63)==0) as[w]=ss;
  __syncthreads();
  if(t==0) ss01[row]=(as[0]+as[1]+as[2]+as[3])/(float)L0;
}

// ---------------- stage-0 conv2 MFMA (store path): y2 = W2 · Xeff, split-bf16 W ------
__global__ __launch_bounds__(256)
void s0conv2_mfma_kernel(const float* __restrict__ W2, const bf16* __restrict__ feat,
                         const float* __restrict__ W1,
                         const float* __restrict__ m1v, const float* __restrict__ rs1v,
                         const float* __restrict__ g1v, const float* __restrict__ rawp,
                         bf16* __restrict__ y2out){
  __shared__ __align__(16) bf16 sW[2][64][40];   // [hi/lo][o][k]
  __shared__ __align__(16) bf16 sXT[128][40];    // [l][k]
  __shared__ float f6[6][128];
  __shared__ float w1s[192][6];
  __shared__ float cmv[192], crsv[192], cgv[192];
  int t=threadIdx.x, b=blockIdx.z, o0=blockIdx.y*64, l0=blockIdx.x*128;
  for(int u=t;u<768;u+=256){ int i=u>>7, lc=u&127; f6[i][lc]=b2f(feat[((size_t)(b*6+i))*L0+l0+lc]); }
  for(int u=t;u<1152;u+=256){ w1s[u/6][u%6]=W1[u]; }
  for(int u=t;u<192;u+=256){ int r=b*C0+u; cmv[u]=m1v[r]; crsv[u]=rs1v[r]; cgv[u]=g1v[r]; }
  int wv=t>>6, lane=t&63, nn=lane&15, quad=lane>>4, kb=quad*8;
  int il=t&31, lq=(t>>5)*16;
  f32x4 acc[8];
  #pragma unroll
  for(int i=0;i<8;i++) acc[i]=(f32x4){0.f,0.f,0.f,0.f};
  __syncthreads();
  for(int c=0;c<12;c++){
    int i0=c*32;
    for(int u=t;u<2048;u+=256){
      int oo=u>>5, kk=u&31;
      float w=W2[(size_t)(o0+oo)*384 + i0+kk];
      bf16 hi=f2b(w);
      sW[0][oo][kk]=hi;
      sW[1][oo][kk]=f2b(w-b2f(hi));
    }
    {
      int i=i0+il;
      if(i<192){
        float pv=cgv[i]*rawp[((size_t)(b*C0+i))*M0 + ((l0+lq)>>5)];
        bf16 pb_=f2b(pv);
        #pragma unroll
        for(int u=0;u<16;u++) sXT[lq+u][il]=pb_;
      } else {
        int cc=i-192;
        float w6[6];
        #pragma unroll
        for(int j=0;j<6;j++) w6[j]=w1s[cc][j];
        float mm=cmv[cc], rr=crsv[cc], gg=cgv[cc];
        #pragma unroll
        for(int u=0;u<16;u++){
          float y=0.f;
          #pragma unroll
          for(int j=0;j<6;j++) y=fmaf(w6[j], f6[j][lq+u], y);
          sXT[lq+u][il]=f2b(gg*fmaxf((y-mm)*rr,0.f));
        }
      }
    }
    __syncthreads();
    bf16x8 aHi=*(const bf16x8*)&sW[0][wv*16+nn][kb];
    bf16x8 aLo=*(const bf16x8*)&sW[1][wv*16+nn][kb];
    #pragma unroll
    for(int lt=0;lt<8;lt++){
      bf16x8 bfr_=*(const bf16x8*)&sXT[lt*16+nn][kb];
      acc[lt]=__builtin_amdgcn_mfma_f32_16x16x32_bf16(aHi,bfr_,acc[lt],0,0,0);
      acc[lt]=__builtin_amdgcn_mfma_f32_16x16x32_bf16(aLo,bfr_,acc[lt],0,0,0);
    }
    __syncthreads();
  }
  #pragma unroll
  for(int lt=0;lt<8;lt++){
    int l=l0+lt*16+nn;
    #pragma unroll
    for(int r=0;r<4;r++){
      int o=o0+wv*16+quad*4+r;
      y2out[((size_t)(b*C0+o))*L0 + l]=f2b(acc[lt][r]);
    }
  }
}

// ---------------- generic MFMA conv (stage-1): Y = (Whi+Wlo)·Xeff ----------------
// Whi/Wlo pre-split bf16, [O][Kpad] (zero-padded). CAT: Xeff = concat(pmax, g*X).
template<bool CAT>
__global__ __launch_bounds__(256)
void conv_mfma_kernel(const bf16* __restrict__ Whi, const bf16* __restrict__ Wlo,
                      const bf16* __restrict__ X, bf16* __restrict__ Y,
                      int I, int Kpad, int L, int M, size_t xbs, size_t ybs,
                      const float* __restrict__ pmax, const float* __restrict__ g,
                      size_t pbs, size_t gbs, int Cc){
  __shared__ __align__(16) bf16 sW[2][64][40];
  __shared__ __align__(16) bf16 sXT[128][40];
  int t=threadIdx.x, z=blockIdx.z, o0=blockIdx.y*64, l0=blockIdx.x*128;
  const bf16* Xb = X + (size_t)z*xbs;
  bf16* Yb = Y + (size_t)z*ybs;
  const float* pm = CAT ? (pmax + (size_t)z*pbs) : nullptr;
  const float* gz = CAT ? (g + (size_t)z*gbs) : nullptr;
  int wv=t>>6, lane=t&63, nn=lane&15, quad=lane>>4, kb=quad*8;
  int il=t&31, lq=(t>>5)*16;
  f32x4 acc[8];
  #pragma unroll
  for(int i=0;i<8;i++) acc[i]=(f32x4){0.f,0.f,0.f,0.f};
  int nch=Kpad/32;
  for(int c=0;c<nch;c++){
    int i0=c*32;
    for(int u=t;u<2048;u+=256){
      int oo=u>>5, kk=u&31;
      sW[0][oo][kk]=Whi[(size_t)(o0+oo)*Kpad + i0+kk];
      sW[1][oo][kk]=Wlo[(size_t)(o0+oo)*Kpad + i0+kk];
    }
    {
      int i=i0+il;
      if(!CAT){
        if(i<I){
          const bf16* xp = Xb + (size_t)i*L + l0 + lq;
          bf16 tmp[16];
          *(uint4*)&tmp[0]=*(const uint4*)xp;
          *(uint4*)&tmp[8]=*(const uint4*)(xp+8);
          #pragma unroll
          for(int u=0;u<16;u++) sXT[lq+u][il]=tmp[u];
        } else {
          bf16 z0=f2b(0.f);
          #pragma unroll
          for(int u=0;u<16;u++) sXT[lq+u][il]=z0;
        }
      } else {
        if(i<Cc){
          float pv=pm[(size_t)i*M + ((l0+lq)>>5)];
          bf16 pb_=f2b(pv);
          #pragma unroll
          for(int u=0;u<16;u++) sXT[lq+u][il]=pb_;
        } else {
          int ii=i-Cc;
          float gg=gz[ii];
          const bf16* xp = Xb + (size_t)ii*L + l0 + lq;
          bf16 tmp[16];
          *(uint4*)&tmp[0]=*(const uint4*)xp;
          *(uint4*)&tmp[8]=*(const uint4*)(xp+8);
          #pragma unroll
          for(int u=0;u<16;u++) sXT[lq+u][il]=f2b(b2f(tmp[u])*gg);
        }
      }
    }
    __syncthreads();
    bf16x8 aHi=*(const bf16x8*)&sW[0][wv*16+nn][kb];
    bf16x8 aLo=*(const bf16x8*)&sW[1][wv*16+nn][kb];
    #pragma unroll
    for(int lt=0;lt<8;lt++){
      bf16x8 bfr_=*(const bf16x8*)&sXT[lt*16+nn][kb];
      acc[lt]=__builtin_amdgcn_mfma_f32_16x16x32_bf16(aHi,bfr_,acc[lt],0,0,0);
      acc[lt]=__builtin_amdgcn_mfma_f32_16x16x32_bf16(aLo,bfr_,acc[lt],0,0,0);
    }
    __syncthreads();
  }
  #pragma unroll
  for(int lt=0;lt<8;lt++){
    int l=l0+lt*16+nn;
    #pragma unroll
    for(int r=0;r<4;r++){
      int o=o0+wv*16+quad*4+r;
      Yb[(size_t)o*L + l]=f2b(acc[lt][r]);
    }
  }
}

// split f32 weights into hi/lo bf16, zero-padded to Kpad
__global__ __launch_bounds__(256)
void wsplit_kernel(const float* __restrict__ W, bf16* __restrict__ hi, bf16* __restrict__ lo,
                   int I, int Kpad, int n){
  int idx=blockIdx.x*256+threadIdx.x;
  if(idx>=n) return;
  int o=idx/Kpad, k=idx%Kpad;
  float w = (k<I) ? W[(size_t)o*I+k] : 0.f;
  bf16 h=f2b(w);
  hi[idx]=h;
  lo[idx]=f2b(w-b2f(h));
}

// ---------------- stage-0 conv2 VALU (fallback path, ws too small) ----------------
template<int PB>
__global__ __launch_bounds__(256)
void s0conv2_kernel(const float* __restrict__ W2, const bf16* __restrict__ feat,
                    const float* __restrict__ W1,
                    const float* __restrict__ m1v, const float* __restrict__ rs1v,
                    const float* __restrict__ g1v, const float* __restrict__ rawp,
                    float* __restrict__ sumA,
                    const float* __restrict__ m2v, const float* __restrict__ rs2v,
                    float* __restrict__ ssum2, float* __restrict__ rawm2){
  __shared__ float sW[96][17];
  __shared__ float sX[16][132];
  __shared__ float f6[6][128];
  __shared__ float w1s[192][6];
  __shared__ float cm[192], crs[192], cg[192];
  int t=threadIdx.x, b=blockIdx.z, o0=blockIdx.y*96, l0=blockIdx.x*128;
  for(int u=t;u<768;u+=256){ int i=u>>7, lc=u&127; f6[i][lc]=b2f(feat[((size_t)(b*6+i))*L0+l0+lc]); }
  for(int u=t;u<1152;u+=256){ w1s[u/6][u%6]=W1[u]; }
  for(int u=t;u<192;u+=256){ int r=b*C0+u; cm[u]=m1v[r]; crs[u]=rs1v[r]; cg[u]=g1v[r]; }
  __syncthreads();
  float acc[6][8];
  #pragma unroll
  for(int r=0;r<6;r++)
    #pragma unroll
    for(int c=0;c<8;c++) acc[r][c]=0.f;
  int to=t>>4, tl=t&15, oL=to*6;
  int xr=to, cA=tl*4;
  int mg0=(l0+cA)>>5;
  for(int i0=0;i0<384;i0+=16){
    #pragma unroll
    for(int u=0;u<6;u++){ int flat=u*256+t, r=flat>>4, ci=flat&15;
      sW[r][ci]=W2[(size_t)(o0+r)*384 + i0+ci]; }
    {
      int i=i0+xr;
      float v[8];
      if(i<192){
        float pv0=cg[i]*rawp[((size_t)(b*C0+i))*M0 + mg0];
        float pv1=cg[i]*rawp[((size_t)(b*C0+i))*M0 + mg0+2];
        v[0]=pv0; v[1]=pv0; v[2]=pv0; v[3]=pv0;
        v[4]=pv1; v[5]=pv1; v[6]=pv1; v[7]=pv1;
      } else {
        int c=i-192;
        #pragma unroll
        for(int u=0;u<4;u++){
          float y=0.f;
          #pragma unroll
          for(int j=0;j<6;j++) y=fmaf(w1s[c][j], f6[j][cA+u], y);
          v[u]=cg[c]*fmaxf((y-cm[c])*crs[c],0.f);
        }
        #pragma unroll
        for(int u=0;u<4;u++){
          float y=0.f;
          #pragma unroll
          for(int j=0;j<6;j++) y=fmaf(w1s[c][j], f6[j][64+cA+u], y);
          v[4+u]=cg[c]*fmaxf((y-cm[c])*crs[c],0.f);
        }
      }
      *(float4*)&sX[xr][cA]    = make_float4(v[0],v[1],v[2],v[3]);
      *(float4*)&sX[xr][64+cA] = make_float4(v[4],v[5],v[6],v[7]);
    }
    __syncthreads();
    #pragma unroll
    for(int kk=0;kk<16;kk++){
      float av[6];
      #pragma unroll
      for(int r=0;r<6;r++) av[r]=sW[oL+r][kk];
      float4 xa=*(const float4*)&sX[kk][cA];
      float4 xb=*(const float4*)&sX[kk][64+cA];
      float xv[8]={xa.x,xa.y,xa.z,xa.w,xb.x,xb.y,xb.z,xb.w};
      #pragma unroll
      for(int r=0;r<6;r++)
        #pragma unroll
        for(int c=0;c<8;c++) acc[r][c]=fmaf(av[r],xv[c],acc[r][c]);
    }
    __syncthreads();
  }
  if(PB==0){
    #pragma unroll
    for(int r=0;r<6;r++){
      float ps=0.f, ps2=0.f;
      #pragma unroll
      for(int c=0;c<8;c++){ ps+=acc[r][c]; ps2+=acc[r][c]*acc[r][c]; }
      #pragma unroll
      for(int off=8;off>0;off>>=1){ ps+=__shfl_down(ps,off,64); ps2+=__shfl_down(ps2,off,64); }
      if(tl==0){ int o=b*C0+o0+oL+r; atomicAdd(&sumA[o],ps); atomicAdd(&sumA[768+o],ps2); }
    }
  } else {
    #pragma unroll
    for(int r=0;r<6;r++){
      int o=b*C0+o0+oL+r;
      float mm=m2v[o], rr=rs2v[o];
      float ps=0.f;
      float mxA=-3e38f, mxB=-3e38f;
      #pragma unroll
      for(int c=0;c<4;c++){ float x=fmaxf((acc[r][c]-mm)*rr,0.f); ps+=x; mxA=fmaxf(mxA,x); }
      #pragma unroll
      for(int c=4;c<8;c++){ float x=fmaxf((acc[r][c]-mm)*rr,0.f); ps+=x; mxB=fmaxf(mxB,x); }
      #pragma unroll
      for(int off=8;off>0;off>>=1) ps+=__shfl_down(ps,off,64);
      if(tl==0) atomicAdd(&ssum2[o], ps);
      mxA=fmaxf(mxA,__shfl_down(mxA,4,64)); mxB=fmaxf(mxB,__shfl_down(mxB,4,64));
      mxA=fmaxf(mxA,__shfl_down(mxA,2,64)); mxB=fmaxf(mxB,__shfl_down(mxB,2,64));
      mxA=fmaxf(mxA,__shfl_down(mxA,1,64)); mxB=fmaxf(mxB,__shfl_down(mxB,1,64));
      if(tl==0){ rawm2[(size_t)o*M0 + (l0>>5)    ] = mxA;
                 rawm2[(size_t)o*M0 + (l0>>5) + 2] = mxB; }
      if(tl==8){ rawm2[(size_t)o*M0 + (l0>>5) + 1] = mxA;
                 rawm2[(size_t)o*M0 + (l0>>5) + 3] = mxB; }
    }
  }
}

// ---------------- y2 streaming pool (store path): mean + per-32 max ----------------
__global__ __launch_bounds__(256)
void s0y2_pool_kernel(const bf16* __restrict__ y2, const float* __restrict__ m2v,
                      const float* __restrict__ rs2v,
                      float* __restrict__ rawm2, float* __restrict__ ss02){
  int row=blockIdx.x, t=threadIdx.x;
  const bf16* yr=y2 + (size_t)row*L0;
  float m=m2v[row], rs=rs2v[row];
  float ss=0.f;
  for(int base=t*8;base<L0;base+=2048){
    uint4 r=*(const uint4*)(yr+base);
    float v[8]; unpack8(r,v);
    float mx=-3e38f;
    #pragma unroll
    for(int u=0;u<8;u++){
      float x=fmaxf((v[u]-m)*rs,0.f);
      ss+=x; mx=fmaxf(mx,x);
    }
    mx=fmaxf(mx,__shfl_down(mx,2,64));
    mx=fmaxf(mx,__shfl_down(mx,1,64));
    if((t&3)==0) rawm2[(size_t)row*M0 + (base>>5)] = mx;
  }
  #pragma unroll
  for(int off=32;off>0;off>>=1) ss+=__shfl_down(ss,off,64);
  __shared__ float as[4];
  int w=t>>6;
  if((t&63)==0) as[w]=ss;
  __syncthreads();
  if(t==0) ss02[row]=(as[0]+as[1]+as[2]+as[3])/(float)L0;
}

__global__ __launch_bounds__(256)
void fin_stats_kernel(const float* __restrict__ sums, float invL, int n,
                      float* __restrict__ mp, float* __restrict__ rp){
  int i=blockIdx.x*256+threadIdx.x;
  if(i<n){
    float m=sums[i]*invL;
    float v=sums[n+i]*invL - m*m;
    v=fmaxf(v,0.f);
    mp[i]=m; rp[i]=rsqrtf(v+1e-5f);
  }
}

__global__ __launch_bounds__(256)
void f1fin_kernel(const float* __restrict__ g2, float* __restrict__ rawm,
                  float* __restrict__ outF1){
  int idx=blockIdx.x*256+threadIdx.x;
  int row=idx>>11;
  float v=g2[row]*rawm[idx];
  rawm[idx]=v;
  outF1[idx]=v;
}

// ---------------- stage-1 ----------------
__global__ __launch_bounds__(256)
void feat1_kernel(int bbase, const float* __restrict__ cp1f, const float* __restrict__ cp2f,
                  const float* __restrict__ f1f, const int* __restrict__ idx1,
                  const int* __restrict__ gid1, bf16* __restrict__ featb){
  int t=blockIdx.x*256+threadIdx.x;
  int bloc=t>>14, l=t&16383;
  int b=bbase+bloc;
  int m=l>>5;
  int j=gid1[((size_t)b*M1+m)*32 + (l&31)];
  int sel=idx1[b*M1+m];
  const float* pj=cp1f + ((size_t)b*M0+j)*3;
  const float* cm=cp2f + ((size_t)b*M1+m)*3;
  bf16* fb=featb + (size_t)bloc*195*L1;
  fb[l]       =f2b(pj[0]-cm[0]);
  fb[L1+l]    =f2b(pj[1]-cm[1]);
  fb[2*L1+l]  =f2b(pj[2]-cm[2]);
  const float* fB=f1f + (size_t)b*C0*M0;
  for(int c=0;c<C0;c++)
    fb[(size_t)(3+c)*L1+l]=f2b(fB[(size_t)c*M0+j]-fB[(size_t)c*M0+sel]);
}

template<bool CAT>
__global__ __launch_bounds__(256)
void conv_b_kernel(const float* __restrict__ W, const bf16* __restrict__ X, bf16* __restrict__ Y,
                   int I, int L, int M, size_t xbs, size_t ybs,
                   const float* __restrict__ pmax, const float* __restrict__ g,
                   size_t pbs, size_t gbs, int Cc){
  __shared__ float sX[16][132];
  __shared__ float sW[96][17];
  int t=threadIdx.x, z=blockIdx.z;
  int o0=blockIdx.y*96, l0=blockIdx.x*128;
  const bf16* Xb = X + (size_t)z*xbs;
  bf16* Yb = Y + (size_t)z*ybs;
  const float* pm = CAT ? (pmax + (size_t)z*pbs) : nullptr;
  const float* gz = CAT ? (g + (size_t)z*gbs) : nullptr;
  float acc[6][8];
  #pragma unroll
  for(int r=0;r<6;r++)
    #pragma unroll
    for(int c=0;c<8;c++) acc[r][c]=0.f;
  int to=t>>4, tl=t&15, oL=to*6;
  int xr=to, cA=tl*4;
  int mg0=(l0+cA)>>5;
  for(int i0=0;i0<I;i0+=16){
    #pragma unroll
    for(int u=0;u<6;u++){
      int flat=u*256+t, r=flat>>4, ci=flat&15, i=i0+ci;
      sW[r][ci] = (i<I) ? W[(size_t)(o0+r)*I+i] : 0.f;
    }
    {
      int i=i0+xr;
      float v[8];
      if(!CAT){
        if(i<I){
          const bf16* xp = Xb + (size_t)i*L + l0;
          uint2 ra=*(const uint2*)(xp+cA);
          uint2 rb=*(const uint2*)(xp+64+cA);
          unpack4(ra,v); unpack4(rb,v+4);
        } else {
          #pragma unroll
          for(int u=0;u<8;u++) v[u]=0.f;
        }
      } else {
        if(i<Cc){
          float pv0=pm[(size_t)i*M + mg0];
          float pv1=pm[(size_t)i*M + mg0+2];
          v[0]=pv0; v[1]=pv0; v[2]=pv0; v[3]=pv0;
          v[4]=pv1; v[5]=pv1; v[6]=pv1; v[7]=pv1;
        } else {
          int ii=i-Cc;
          float gg=gz[ii];
          const bf16* xp = Xb + (size_t)ii*L + l0;
          uint2 ra=*(const uint2*)(xp+cA);
          uint2 rb=*(const uint2*)(xp+64+cA);
          unpack4(ra,v); unpack4(rb,v+4);
          #pragma unroll
          for(int u=0;u<8;u++) v[u]*=gg;
        }
      }
      *(float4*)&sX[xr][cA]    = make_float4(v[0],v[1],v[2],v[3]);
      *(float4*)&sX[xr][64+cA] = make_float4(v[4],v[5],v[6],v[7]);
    }
    __syncthreads();
    #pragma unroll
    for(int kk=0;kk<16;kk++){
      float av[6];
      #pragma unroll
      for(int r=0;r<6;r++) av[r]=sW[oL+r][kk];
      float4 xa=*(const float4*)&sX[kk][cA];
      float4 xb=*(const float4*)&sX[kk][64+cA];
      float xv[8]={xa.x,xa.y,xa.z,xa.w,xb.x,xb.y,xb.z,xb.w};
      #pragma unroll
      for(int r=0;r<6;r++)
        #pragma unroll
        for(int c=0;c<8;c++) acc[r][c]=fmaf(av[r],xv[c],acc[r][c]);
    }
    __syncthreads();
  }
  #pragma unroll
  for(int r=0;r<6;r++){
    bf16* yp=Yb + (size_t)(o0+oL+r)*L + l0;
    #pragma unroll
    for(int c=0;c<4;c++) yp[cA+c]=f2b(acc[r][c]);
    #pragma unroll
    for(int c=0;c<4;c++) yp[64+cA+c]=f2b(acc[r][4+c]);
  }
}

__global__ __launch_bounds__(256)
void rowstats_kernel(const bf16* __restrict__ Y, int L,
                     float* __restrict__ meanp, float* __restrict__ rstdp){
  int row=blockIdx.x;
  const uint4* yr=(const uint4*)(Y + (size_t)row*L);
  int nv=L/8;
  float s=0.f, s2=0.f;
  for(int i=threadIdx.x;i<nv;i+=256){
    uint4 r=yr[i]; float v[8]; unpack8(r,v);
    #pragma unroll
    for(int u=0;u<8;u++){ s+=v[u]; s2+=v[u]*v[u]; }
  }
  #pragma unroll
  for(int off=32;off>0;off>>=1){ s+=__shfl_down(s,off,64); s2+=__shfl_down(s2,off,64); }
  __shared__ float as[4], bs[4];
  int w=threadIdx.x>>6;
  if((threadIdx.x&63)==0){ as[w]=s; bs[w]=s2; }
  __syncthreads();
  if(threadIdx.x==0){
    float S=as[0]+as[1]+as[2]+as[3], S2=bs[0]+bs[1]+bs[2]+bs[3];
    float m=S/(float)L, var=S2/(float)L - m*m;
    var=fmaxf(var,0.f);
    meanp[row]=m; rstdp[row]=rsqrtf(var+1e-5f);
  }
}

__global__ __launch_bounds__(256)
void normrelu_kernel(bf16* __restrict__ Y, int L, const float* __restrict__ meanp,
                     const float* __restrict__ rstdp, float* __restrict__ ssum){
  int row=blockIdx.x;
  float m=meanp[row], rs=rstdp[row];
  uint4* yr=(uint4*)(Y + (size_t)row*L);
  int nv=L/8;
  float s=0.f;
  for(int i=threadIdx.x;i<nv;i+=256){
    uint4 r=yr[i]; float v[8]; unpack8(r,v);
    #pragma unroll
    for(int u=0;u<8;u++){ float x=(v[u]-m)*rs; x=fmaxf(x,0.f); v[u]=x; s+=x; }
    uint4 o; o.x=pk2(v[0],v[1]); o.y=pk2(v[2],v[3]); o.z=pk2(v[4],v[5]); o.w=pk2(v[6],v[7]);
    yr[i]=o;
  }
  #pragma unroll
  for(int off=32;off>0;off>>=1) s+=__shfl_down(s,off,64);
  __shared__ float as[4];
  int w=threadIdx.x>>6;
  if((threadIdx.x&63)==0) as[w]=s;
  __syncthreads();
  if(threadIdx.x==0) ssum[row]=(as[0]+as[1]+as[2]+as[3])/(float)L;
}

__global__ __launch_bounds__(256)
void attn_kernel(const float* __restrict__ ssum, const float* __restrict__ w1,
                 const float* __restrict__ w2, int Cc, int H, float* __restrict__ g,
                 float scale){
  __shared__ float sv[384]; __shared__ float hv[96];
  int b=blockIdx.x, t=threadIdx.x;
  for(int i=t;i<Cc;i+=256) sv[i]=ssum[b*Cc+i]*scale;
  __syncthreads();
  if(t<H){
    float a=0.f;
    for(int c=0;c<Cc;c++) a+=w1[(size_t)t*Cc+c]*sv[c];
    hv[t]=fmaxf(a,0.f);
  }
  __syncthreads();
  for(int o=t;o<Cc;o+=256){
    float a=0.f;
    for(int j=0;j<H;j++) a+=w2[(size_t)o*H+j]*hv[j];
    g[b*Cc+o]=1.f/(1.f+expf(-a));
  }
}

__global__ __launch_bounds__(256)
void pmax_kernel(const bf16* __restrict__ Xn, const float* __restrict__ g,
                 int Mloc, float* __restrict__ pm){
  int row=blockIdx.y;
  int m=blockIdx.x*256+threadIdx.x;
  const uint4* x=(const uint4*)(Xn + (size_t)row*Mloc*32 + (size_t)m*32);
  float mv=-3.0e38f;
  #pragma unroll
  for(int i=0;i<4;i++){
    uint4 r=x[i]; float v[8]; unpack8(r,v);
    #pragma unroll
    for(int u=0;u<8;u++) mv=fmaxf(mv,v[u]);
  }
  pm[(size_t)row*Mloc+m]=g[row]*mv;
}

__global__ __launch_bounds__(256)
void fmax_out_kernel(const bf16* __restrict__ Xn, const float* __restrict__ g,
                     int Mloc, float* __restrict__ outp){
  int row=blockIdx.y;
  int m=blockIdx.x*256+threadIdx.x;
  const uint4* x=(const uint4*)(Xn + (size_t)row*Mloc*32 + (size_t)m*32);
  float mv=-3.0e38f;
  #pragma unroll
  for(int i=0;i<4;i++){
    uint4 r=x[i]; float v[8]; unpack8(r,v);
    #pragma unroll
    for(int u=0;u<8;u++) mv=fmaxf(mv,v[u]);
  }
  outp[(size_t)row*Mloc+m]=g[row]*mv;
}

extern "C" void kernel_launch(void* const* d_in, const int* in_sizes, int n_in,
                              void* d_out, int out_size, void* d_ws, size_t ws_size,
                              hipStream_t stream){
  // ---- order-proof input routing by element count ----
  const float* PF[2]={nullptr,nullptr}; int npf=0;
  const float* A9[4]={0,0,0,0};  int n9=0;
  const float* A36[4]={0,0,0,0}; int n36=0;
  const float *s0_w1=0,*s0_w2=0,*s1_w1=0,*s1_w2=0;
  for(int i=0;i<n_in;i++){
    const float* ptr=(const float*)d_in[i];
    switch(in_sizes[i]){
      case 98304:  if(npf<2) PF[npf++]=ptr; break;
      case 1152:   s0_w1=ptr; break;
      case 73728:  s0_w2=ptr; break;
      case 74880:  s1_w1=ptr; break;
      case 294912: s1_w2=ptr; break;
      case 9216:   if(n9<4)  A9[n9++]=ptr;  break;
      case 36864:  if(n36<4) A36[n36++]=ptr; break;
      default: break;
    }
  }
  const float* s0_a1w1=A9[0];  const float* s0_a1w2=A9[1];
  const float* s0_a2w1=A9[2];  const float* s0_a2w2=A9[3];
  const float* s1_a1w1=A36[0]; const float* s1_a1w2=A36[1];
  const float* s1_a2w1=A36[2]; const float* s1_a2w2=A36[3];

  float* out=(float*)d_out;
  char* ws=(char*)d_ws;

  int*   flag =(int*)  (ws+A_FLAG);
  float* cp1f =(float*)(ws+A_CP1F);
  float* cp2f =(float*)(ws+A_CP2F);
  int*   idx0 =(int*)  (ws+A_IDX0);
  int*   idx1 =(int*)  (ws+A_IDX1);
  int*   gid0 =(int*)  (ws+A_GID0);
  int*   gid1 =(int*)  (ws+A_GID1);
  bf16*  feat0=(bf16*) (ws+A_FEAT0);
  float* m1v  =(float*)(ws+A_M1V);
  float* rs1v =(float*)(ws+A_RS1V);
  float* ss01 =(float*)(ws+A_SS01);
  float* g1v  =(float*)(ws+A_G1V);
  float* sumA =(float*)(ws+A_SUMA);
  float* ss02 =(float*)(ws+A_SS02);
  float* m2v  =(float*)(ws+A_M2V);
  float* rs2v =(float*)(ws+A_RS2V);
  float* g2v  =(float*)(ws+A_G2V);
  float* rawp =(float*)(ws+A_RAWP);
  float* rawm2=(float*)(ws+A_RAWM2);
  float* f1f  =rawm2;
  bf16*  y2s0 =(bf16*) (ws+A_Y2);

  detect_kernel<<<1,64,0,stream>>>(PF[0], flag);
  cvt_pf_kernel<<<384,256,0,stream>>>(PF[0], PF[1], flag, out+OUT_P, out+OUT_F, B_*N0*3);

  // ---- stage 0: sampling/grouping ----
  fps_kernel<N0,M0,512><<<B_,512,0,stream>>>(PF[0], PF[1], flag, idx0);
  gather_cp_kernel<<<32,256,0,stream>>>(PF[0], PF[1], flag, idx0, N0, M0, cp1f, out+OUT_CP1);
  ballq_kernel<N0,M0><<<dim3(32,B_),256,0,stream>>>(PF[0], PF[1], flag, cp1f, gid0);
  feat0_kernel<<<1024,256,0,stream>>>(PF[0], PF[1], flag, cp1f, idx0, gid0, feat0);

  // ---- stage 0: conv block 1 (virtual) ----
  s0c1_stats_kernel<<<B_*C0,256,0,stream>>>(feat0, s0_w1, m1v, rs1v);
  s0c1_pool_kernel<<<B_*C0,256,0,stream>>>(feat0, s0_w1, m1v, rs1v, rawp, ss01);
  attn_kernel<<<B_,256,0,stream>>>(ss01, s0_a1w1, s0_a1w2, C0, H0, g1v, 1.f);

  // ---- stage 0: conv block 2 ----
  if(ws_size >= WS_Y2){
    s0conv2_mfma_kernel<<<dim3(512,3,B_),256,0,stream>>>(s0_w2, feat0, s0_w1, m1v, rs1v, g1v, rawp, y2s0);
    rowstats_kernel<<<B_*C0,256,0,stream>>>(y2s0, L0, m2v, rs2v);
    s0y2_pool_kernel<<<B_*C0,256,0,stream>>>(y2s0, m2v, rs2v, rawm2, ss02);
    attn_kernel<<<B_,256,0,stream>>>(ss02, s0_a2w1, s0_a2w2, C0, H0, g2v, 1.f);
  } else {
    hipMemsetAsync(ws+A_SUMA, 0, 9216, stream);
    s0conv2_kernel<0><<<dim3(512,2,B_),256,0,stream>>>(s0_w2, feat0, s0_w1, m1v, rs1v, g1v,
                                                       rawp, sumA, nullptr,nullptr,nullptr,nullptr);
    fin_stats_kernel<<<3,256,0,stream>>>(sumA, 1.f/(float)L0, 768, m2v, rs2v);
    s0conv2_kernel<1><<<dim3(512,2,B_),256,0,stream>>>(s0_w2, feat0, s0_w1, m1v, rs1v, g1v,
                                                       rawp, nullptr, m2v, rs2v, ss02, rawm2);
    attn_kernel<<<B_,256,0,stream>>>(ss02, s0_a2w1, s0_a2w2, C0, H0, g2v, 1.f/(float)L0);
  }
  f1fin_kernel<<<6144,256,0,stream>>>(g2v, rawm2, out+OUT_F1);

  // ---- stage 1: sampling/grouping ----
  fps_kernel<M0,M1,512><<<B_,512,0,stream>>>(cp1f, cp1f, nullptr, idx1);
  gather_cp_kernel<<<8,256,0,stream>>>(cp1f, cp1f, nullptr, idx1, M0, M1, cp2f, out+OUT_CP2);
  ballq_kernel<M0,M1><<<dim3(8,B_),256,0,stream>>>(cp1f, cp1f, nullptr, cp2f, gid1);

  if(ws_size >= A_NEED){
    // ---- batch-parallel stage 1 ----
    bf16*  f1a =(bf16*) (ws+A_F1A);
    bf16*  yb1a=(bf16*) (ws+A_YB1A);
    bf16*  yb2a=(bf16*) (ws+A_YB2A);
    float* pma =(float*)(ws+A_PMA);
    float* msa =(float*)(ws+A_MSA);
    float* rsa =(float*)(ws+A_RSA);
    float* ssa =(float*)(ws+A_SSA);
    float* g1a =(float*)(ws+A_G1A);
    float* g2a =(float*)(ws+A_G2A);
    bool mfma1 = (ws_size >= A_NEED2);
    bf16* w1h=(bf16*)(ws+A_W1H); bf16* w1l=(bf16*)(ws+A_W1L);
    bf16* w2h=(bf16*)(ws+A_W2H); bf16* w2l=(bf16*)(ws+A_W2L);
    if(mfma1){
      wsplit_kernel<<<(384*224+255)/256,256,0,stream>>>(s1_w1, w1h, w1l, 195, 224, 384*224);
      wsplit_kernel<<<(384*768+255)/256,256,0,stream>>>(s1_w2, w2h, w2l, 768, 768, 384*768);
    }
    feat1_kernel<<<B_*L1/256,256,0,stream>>>(0, cp1f, cp2f, f1f, idx1, gid1, f1a);
    if(mfma1)
      conv_mfma_kernel<false><<<dim3(L1/128,C1/64,B_),256,0,stream>>>(w1h, w1l, f1a, yb1a,
                                 195, 224, L1, M1, (size_t)195*L1, (size_t)C1*L1,
                                 nullptr,nullptr,0,0,0);
    else
      conv_b_kernel<false><<<dim3(L1/128,4,B_),256,0,stream>>>(s1_w1, f1a, yb1a, 195, L1, M1,
                                 (size_t)195*L1, (size_t)C1*L1, nullptr,nullptr,0,0,0);
    rowstats_kernel<<<B_*C1,256,0,stream>>>(yb1a, L1, msa, rsa);
    normrelu_kernel<<<B_*C1,256,0,stream>>>(yb1a, L1, msa, rsa, ssa);
    attn_kernel<<<B_,256,0,stream>>>(ssa, s1_a1w1, s1_a1w2, C1, H1, g1a, 1.f);
    pmax_kernel<<<dim3(2,B_*C1),256,0,stream>>>(yb1a, g1a, M1, pma);
    if(mfma1)
      conv_mfma_kernel<true><<<dim3(L1/128,C1/64,B_),256,0,stream>>>(w2h, w2l, yb1a, yb2a,
                                 768, 768, L1, M1, (size_t)C1*L1, (size_t)C1*L1,
                                 pma, g1a, (size_t)C1*M1, (size_t)C1, C1);
    else
      conv_b_kernel<true><<<dim3(L1/128,4,B_),256,0,stream>>>(s1_w2, yb1a, yb2a, 2*C1, L1, M1,
                                 (size_t)C1*L1, (size_t)C1*L1, pma, g1a, (size_t)C1*M1, (size_t)C1, C1);
    rowstats_kernel<<<B_*C1,256,0,stream>>>(yb2a, L1, msa, rsa);
    normrelu_kernel<<<B_*C1,256,0,stream>>>(yb2a, L1, msa, rsa, ssa);
    attn_kernel<<<B_,256,0,stream>>>(ssa, s1_a2w1, s1_a2w2, C1, H1, g2a, 1.f);
    fmax_out_kernel<<<dim3(2,B_*C1),256,0,stream>>>(yb2a, g2a, M1, out+OUT_F2);
  } else {
    // ---- serial fallback ----
    bf16*  feat1b=(bf16*)(ws+A_FEAT1);
    bf16*  ybuf1 =(bf16*)(ws+A_YB1);
    bf16*  ybuf2 =(bf16*)(ws+A_YB2);
    float* pmS1 =(float*)(ws+A_PMS1);
    float* mS1  =(float*)(ws+A_MS1);
    float* rsS1 =(float*)(ws+A_RSS1);
    float* ssS1 =(float*)(ws+A_SSS1);
    float* g1s1 =(float*)(ws+A_G1S1);
    float* g2s1 =(float*)(ws+A_G2S1);
    for(int b=0;b<B_;b++){
      feat1_kernel<<<64,256,0,stream>>>(b, cp1f, cp2f, f1f, idx1, gid1, feat1b);
      conv_b_kernel<false><<<dim3(L1/128,4,1),256,0,stream>>>(s1_w1, feat1b, ybuf1, 195, L1, M1,
                                   0,0, nullptr,nullptr,0,0,0);
      rowstats_kernel<<<C1,256,0,stream>>>(ybuf1, L1, mS1, rsS1);
      normrelu_kernel<<<C1,256,0,stream>>>(ybuf1, L1, mS1, rsS1, ssS1);
      attn_kernel<<<1,256,0,stream>>>(ssS1, s1_a1w1, s1_a1w2, C1, H1, g1s1, 1.f);
      pmax_kernel<<<dim3(2,C1),256,0,stream>>>(ybuf1, g1s1, M1, pmS1);
      conv_b_kernel<true><<<dim3(L1/128,4,1),256,0,stream>>>(s1_w2, ybuf1, ybuf2, 2*C1, L1, M1,
                                   0,0, pmS1, g1s1, 0,0, C1);
      rowstats_kernel<<<C1,256,0,stream>>>(ybuf2, L1, mS1, rsS1);
      normrelu_kernel<<<C1,256,0,stream>>>(ybuf2, L1, mS1, rsS1, ssS1);
      attn_kernel<<<1,256,0,stream>>>(ssS1, s1_a2w1, s1_a2w2, C1, H1, g2s1, 1.f);
      fmax_out_kernel<<<dim3(2,C1),256,0,stream>>>(ybuf2, g2s1, M1, out+OUT_F2+(size_t)b*C1*M1);
    }
  }
}

// Round 11
// 3753.628 us; speedup vs baseline: 1.3230x; 1.3230x over previous
//
#include <hip/hip_runtime.h>
#include <hip/hip_bf16.h>
#include <stdint.h>

typedef __hip_bfloat16 bf16;
typedef unsigned long long u64;
typedef short bf16x8 __attribute__((ext_vector_type(8)));
typedef float f32x4 __attribute__((ext_vector_type(4)));
#define DEVI static __device__ __forceinline__

DEVI float b2f(bf16 v){ return __bfloat162float(v); }
DEVI bf16  f2b(float v){ return __float2bfloat16(v); }
DEVI float bfL(unsigned u){ return __uint_as_float(u<<16); }
DEVI float bfH(unsigned u){ return __uint_as_float(u & 0xffff0000u); }
DEVI void unpack8(uint4 r, float* v){
  v[0]=bfL(r.x); v[1]=bfH(r.x); v[2]=bfL(r.y); v[3]=bfH(r.y);
  v[4]=bfL(r.z); v[5]=bfH(r.z); v[6]=bfL(r.w); v[7]=bfH(r.w);
}
DEVI void unpack4(uint2 r, float* v){
  v[0]=bfL(r.x); v[1]=bfH(r.x); v[2]=bfL(r.y); v[3]=bfH(r.y);
}
DEVI unsigned short bfr(float x){ bf16 h=f2b(x); return *reinterpret_cast<unsigned short*>(&h); }
DEVI unsigned pk2(float a,float b){ return (unsigned)bfr(a) | ((unsigned)bfr(b)<<16); }

constexpr int B_=4, N0=8192, M0=2048, M1=512, KK=32;
constexpr int L0=M0*KK, L1=M1*KK;       // 65536, 16384
constexpr int C0=192, H0=48, C1=384, H1=96;

// ---- output element offsets (FLOAT32), return order: p,cp1,cp2,f,f1,f2 ----
constexpr size_t OUT_P=0, OUT_CP1=98304, OUT_CP2=122880, OUT_F=129024,
                 OUT_F1=227328, OUT_F2=1800192;

// ---- workspace byte offsets ----
constexpr size_t A_FLAG  = 0;
constexpr size_t A_CP1F  = 256;
constexpr size_t A_CP2F  = A_CP1F+98304;
constexpr size_t A_IDX0  = A_CP2F+24576;
constexpr size_t A_IDX1  = A_IDX0+32768;
constexpr size_t A_GID0  = A_IDX1+8192;
constexpr size_t A_GID1  = A_GID0+1048576;
constexpr size_t A_FEAT0 = A_GID1+262144;          // bf16 B*6*L0 = 3145728
constexpr size_t A_M1V   = A_FEAT0+3145728;
constexpr size_t A_RS1V  = A_M1V+3072;
constexpr size_t A_SS01  = A_RS1V+3072;
constexpr size_t A_G1V   = A_SS01+3072;
constexpr size_t A_SUMA  = A_G1V+3072;             // 6144 (atomic, memset)
constexpr size_t A_SS02  = A_SUMA+6144;            // 3072
constexpr size_t A_M2V   = A_SS02+3072;
constexpr size_t A_RS2V  = A_M2V+3072;
constexpr size_t A_G2V   = A_RS2V+3072;
constexpr size_t A_RAWP  = A_G2V+3072;             // f32 B*C0*M0 = 6291456
constexpr size_t A_RAWM2 = A_RAWP+6291456;         // f32 B*C0*M0 (becomes f1f)
constexpr size_t A_FEAT1 = A_RAWM2+6291456;        // = 17234176
// ---- y2 store (stage-0 only; overlaps stage-1 regions temporally) ----
constexpr size_t A_Y2    = A_FEAT1;                // bf16 B*C0*L0 = 100663296
constexpr size_t WS_Y2   = A_Y2 + 100663296;       // 117,897,472
// ---- stage-1 serial-mode buffers ----
constexpr size_t A_YB1   = A_FEAT1+6389760;
constexpr size_t A_YB2   = A_YB1+12582912;
constexpr size_t A_PMS1  = A_YB2+12582912;
constexpr size_t A_MS1   = A_PMS1+786432;
constexpr size_t A_RSS1  = A_MS1+1536;
constexpr size_t A_SSS1  = A_RSS1+1536;
constexpr size_t A_G1S1  = A_SSS1+1536;
constexpr size_t A_G2S1  = A_G1S1+1536;
// ---- stage-1 parallel-mode buffers ----
constexpr size_t A_F1A  = A_FEAT1;                 // bf16 B*195*L1 = 25559040
constexpr size_t A_YB1A = A_F1A + 25559040;
constexpr size_t A_YB2A = A_YB1A + 50331648;
constexpr size_t A_PMA  = A_YB2A + 50331648;
constexpr size_t A_MSA  = A_PMA + 3145728;
constexpr size_t A_RSA  = A_MSA + 6144;
constexpr size_t A_SSA  = A_RSA + 6144;
constexpr size_t A_G1A  = A_SSA + 6144;
constexpr size_t A_G2A  = A_G1A + 6144;
constexpr size_t A_NEED = A_G2A + 6144;            // 146,632,960
// ---- split bf16 weights for stage-1 MFMA convs (hi/lo) ----
constexpr size_t A_W1H  = A_NEED;                  // bf16 384*224
constexpr size_t A_W1L  = A_W1H + 172032;
constexpr size_t A_W2H  = A_W1L + 172032;          // bf16 384*768
constexpr size_t A_W2L  = A_W2H + 589824;
constexpr size_t A_NEED2= A_W2L + 589824;          // ~148.1 MB

DEVI const float* pick(const float* c0, const float* c1, const int* fl, int want_f){
  int sw = fl ? ((*fl)!=0) : 0;
  return (sw ^ want_f) ? c1 : c0;
}

__global__ __launch_bounds__(64)
void detect_kernel(const float* __restrict__ c0, int* __restrict__ flag){
  unsigned long long m = __ballot(c0[threadIdx.x] < 0.f);
  if(threadIdx.x==0) *flag = (m!=0ull) ? 1 : 0;
}

__global__ __launch_bounds__(256)
void cvt_pf_kernel(const float* __restrict__ c0, const float* __restrict__ c1,
                   const int* __restrict__ fl, float* __restrict__ outP,
                   float* __restrict__ outF, int n){
  const float* p = pick(c0,c1,fl,0);
  const float* f = pick(c0,c1,fl,1);
  int i=blockIdx.x*256+threadIdx.x;
  if(i<n){ outP[i]=p[i]; outF[i]=f[i]; }
}

// ---------------- FPS (R9-proven config: TPB256, 2-value DPP, pt4 LDS broadcast) -----
// Epilogue does the centroid gather (sel + cpf + out centroids) from LDS.
#define DPP_ARGMAX(CTRL) { \
  int iv_=__builtin_amdgcn_update_dpp(__float_as_int(bv), __float_as_int(bv), CTRL, 0xF, 0xF, false); \
  int ii_=__builtin_amdgcn_update_dpp(bi, bi, CTRL, 0xF, 0xF, false); \
  float fv_=__int_as_float(iv_); \
  if(fv_>bv || (fv_==bv && ii_<bi)){ bv=fv_; bi=ii_; } }

template<int NP, int MS, int TPB>
__global__ __launch_bounds__(TPB)
void fps_kernel(const float* __restrict__ c0, const float* __restrict__ c1,
                const int* __restrict__ fl, int* __restrict__ sel,
                float* __restrict__ cpf, float* __restrict__ outcp){
  constexpr int CH = NP/TPB;
  constexpr int NW = TPB/64;
  __shared__ float4 pt4[NP];
  __shared__ u64 wvi[2][NW];
  __shared__ int msel[MS];
  const float* pC = pick(c0,c1,fl,0);
  int b=blockIdx.x, t=threadIdx.x;
  const float* pb = pC + (size_t)b*NP*3;
  for(int i=t;i<NP;i+=TPB)
    pt4[i]=make_float4(pb[(size_t)i*3], pb[(size_t)i*3+1], pb[(size_t)i*3+2], 0.f);
  if(t==0) msel[0]=0;
  __syncthreads();
  float ox[CH], oy[CH], oz[CH], dd[CH];
  #pragma unroll
  for(int c=0;c<CH;c++){
    float4 q=pt4[t*CH+c];
    ox[c]=q.x; oy[c]=q.y; oz[c]=q.z;
    dd[c]=1e10f;
  }
  float4 c40=pt4[0];
  float cx=c40.x, cy=c40.y, cz=c40.z;
  int par=0;
  for(int s=1;s<MS;s++){
    float bv=-1.f; int bi=0;
    #pragma unroll
    for(int c=0;c<CH;c++){
      float dx=__fsub_rn(ox[c],cx), dy=__fsub_rn(oy[c],cy), dz=__fsub_rn(oz[c],cz);
      float d=__fadd_rn(__fadd_rn(__fmul_rn(dx,dx),__fmul_rn(dy,dy)),__fmul_rn(dz,dz));
      float nd=fminf(dd[c],d); dd[c]=nd;
      if(nd>bv){ bv=nd; bi=t*CH+c; }   // strict >: first index wins within thread
    }
    DPP_ARGMAX(0x111) DPP_ARGMAX(0x112) DPP_ARGMAX(0x114) DPP_ARGMAX(0x118)
    DPP_ARGMAX(0x142) DPP_ARGMAX(0x143)
    if((t&63)==63)
      wvi[par][t>>6] = (((u64)__float_as_uint(bv))<<32) | (unsigned)(0xFFFFFFFFu-(unsigned)bi);
    __syncthreads();
    u64 best=wvi[par][0];
    #pragma unroll
    for(int k=1;k<NW;k++){ u64 w=wvi[par][k]; if(w>best) best=w; }
    int mi = (int)(0xFFFFFFFFu - (unsigned)best);
    if(t==0) msel[s]=mi;
    float4 c4=pt4[mi];                 // single b128 broadcast (exact f32)
    cx=c4.x; cy=c4.y; cz=c4.z;
    par^=1;
  }
  __syncthreads();
  // epilogue: write sel + gathered centroids (exact f32 from LDS)
  for(int i=t;i<MS;i+=TPB){
    int j=msel[i];
    sel[(size_t)b*MS+i]=j;
    float4 q=pt4[j];
    float* d=cpf + ((size_t)b*MS+i)*3;  d[0]=q.x; d[1]=q.y; d[2]=q.z;
    float* o=outcp + ((size_t)b*MS+i)*3; o[0]=q.x; o[1]=q.y; o[2]=q.z;
  }
}

// ---------------- ball query ----------------
template<int NP, int MS>
__global__ __launch_bounds__(256)
void ballq_kernel(const float* __restrict__ c0, const float* __restrict__ c1,
                  const int* __restrict__ fl, const float* __restrict__ cpf,
                  int* __restrict__ gidx){
  __shared__ int cand[4][64][33];
  __shared__ int ccnt[4][64];
  const float* pC = pick(c0,c1,fl,0);
  int t=threadIdx.x, q=t>>6, cl=t&63;
  int b=blockIdx.y, m=blockIdx.x*64+cl;
  const float* cc=cpf + ((size_t)b*MS+m)*3;
  float cx=cc[0], cy=cc[1], cz=cc[2];
  const float R2=0.01f;
  const float* pb=pC + (size_t)b*NP*3;
  int cnt=0;
  int j0=q*(NP/4), j1=j0+NP/4;
  for(int j=j0;j<j1;j++){
    if(cnt>=32) break;
    float dx=__fsub_rn(cx,pb[(size_t)j*3]);
    float dy=__fsub_rn(cy,pb[(size_t)j*3+1]);
    float dz=__fsub_rn(cz,pb[(size_t)j*3+2]);
    float d2=__fadd_rn(__fadd_rn(__fmul_rn(dx,dx),__fmul_rn(dy,dy)),__fmul_rn(dz,dz));
    if(d2<R2) cand[q][cl][cnt++]=j;
  }
  ccnt[q][cl]=cnt;
  __syncthreads();
  if(q==0){
    int* gp=gidx + ((size_t)b*MS+m)*32;
    int total=0, first=0; bool has=false;
    for(int qq=0;qq<4;qq++){
      int n=ccnt[qq][cl];
      for(int u=0;u<n;u++){
        if(total>=32) break;
        int id=cand[qq][cl][u];
        if(!has){ first=id; has=true; }
        gp[total++]=id;
      }
      if(total>=32) break;
    }
    if(!has){ for(int u=0;u<32;u++) gp[u]=0; }
    else    { for(int u=total;u<32;u++) gp[u]=first; }
  }
}

__global__ __launch_bounds__(256)
void feat0_kernel(const float* __restrict__ c0, const float* __restrict__ c1,
                  const int* __restrict__ fl, const float* __restrict__ cp1f,
                  const int* __restrict__ idx0, const int* __restrict__ gidx0,
                  bf16* __restrict__ feat){
  const float* p0f = pick(c0,c1,fl,0);
  const float* f_in= pick(c0,c1,fl,1);
  int t=blockIdx.x*256+threadIdx.x;
  int b=t>>16, rem=t&65535, m=rem>>5;
  int j=gidx0[t];
  int sel=idx0[(b<<11)+m];
  const float* pj=p0f + ((size_t)(b*N0)+j)*3;
  const float* cm=cp1f + ((size_t)(b*M0)+m)*3;
  bf16* fb=feat + (size_t)b*6*L0 + rem;
  fb[0]      =f2b(pj[0]-cm[0]);
  fb[L0]     =f2b(pj[1]-cm[1]);
  fb[2*L0]   =f2b(pj[2]-cm[2]);
  const float* fI=f_in + (size_t)b*3*N0;
  #pragma unroll
  for(int c=0;c<3;c++)
    fb[(size_t)(3+c)*L0]=f2b(fI[c*N0+j]-fI[c*N0+sel]);
}

// ---------------- stage-0 conv1 stats (I=6) ----------------
__global__ __launch_bounds__(256)
void s0c1_stats_kernel(const bf16* __restrict__ feat, const float* __restrict__ W1,
                       float* __restrict__ m1v, float* __restrict__ rs1v){
  int row=blockIdx.x, b=row/C0, c=row%C0, t=threadIdx.x;
  float w6[6];
  #pragma unroll
  for(int j=0;j<6;j++) w6[j]=W1[c*6+j];
  const bf16* fb=feat + (size_t)b*6*L0;
  float s=0.f,s2=0.f;
  for(int base=t*8;base<L0;base+=2048){
    float X[6][8];
    #pragma unroll
    for(int i=0;i<6;i++){ uint4 r=*(const uint4*)(fb+(size_t)i*L0+base); unpack8(r,X[i]); }
    #pragma unroll
    for(int u=0;u<8;u++){
      float y=0.f;
      #pragma unroll
      for(int j=0;j<6;j++) y=fmaf(w6[j],X[j][u],y);
      s+=y; s2+=y*y;
    }
  }
  #pragma unroll
  for(int off=32;off>0;off>>=1){ s+=__shfl_down(s,off,64); s2+=__shfl_down(s2,off,64); }
  __shared__ float as[4], bs[4];
  int w=t>>6;
  if((t&63)==0){ as[w]=s; bs[w]=s2; }
  __syncthreads();
  if(t==0){
    float S=as[0]+as[1]+as[2]+as[3], S2=bs[0]+bs[1]+bs[2]+bs[3];
    float m=S/(float)L0, var=S2/(float)L0-m*m;
    var=fmaxf(var,0.f);
    m1v[row]=m; rs1v[row]=rsqrtf(var+1e-5f);
  }
}

// ---------------- stage-0 pool: ssum + raw k-max (g1 factored out) ----------------
__global__ __launch_bounds__(256)
void s0c1_pool_kernel(const bf16* __restrict__ feat, const float* __restrict__ W1,
                      const float* __restrict__ m1v, const float* __restrict__ rs1v,
                      float* __restrict__ rawp, float* __restrict__ ss01){
  int row=blockIdx.x, b=row/C0, c=row%C0, t=threadIdx.x;
  float w6[6];
  #pragma unroll
  for(int j=0;j<6;j++) w6[j]=W1[c*6+j];
  const bf16* fb=feat + (size_t)b*6*L0;
  float m=m1v[row], rs=rs1v[row];
  float ss=0.f;
  for(int base=t*8;base<L0;base+=2048){
    float X[6][8];
    #pragma unroll
    for(int i=0;i<6;i++){ uint4 r=*(const uint4*)(fb+(size_t)i*L0+base); unpack8(r,X[i]); }
    float mx=-3e38f;
    #pragma unroll
    for(int u=0;u<8;u++){
      float y=0.f;
      #pragma unroll
      for(int j=0;j<6;j++) y=fmaf(w6[j],X[j][u],y);
      float x=fmaxf((y-m)*rs,0.f);
      ss+=x; mx=fmaxf(mx,x);
    }
    mx=fmaxf(mx,__shfl_down(mx,2,64));
    mx=fmaxf(mx,__shfl_down(mx,1,64));
    if((t&3)==0) rawp[(size_t)row*M0 + (base>>5)] = mx;
  }
  #pragma unroll
  for(int off=32;off>0;off>>=1) ss+=__shfl_down(ss,off,64);
  __shared__ float as[4];
  int w=t>>6;
  if((t&63)==0) as[w]=ss;
  __syncthreads();
  if(t==0) ss01[row]=(as[0]+as[1]+as[2]+as[3])/(float)L0;
}

// ---------------- stage-0 conv2 MFMA: y2 = W2·Xeff (split-bf16 W) + atomic stats -----
__global__ __launch_bounds__(256)
void s0conv2_mfma_kernel(const float* __restrict__ W2, const bf16* __restrict__ feat,
                         const float* __restrict__ W1,
                         const float* __restrict__ m1v, const float* __restrict__ rs1v,
                         const float* __restrict__ g1v, const float* __restrict__ rawp,
                         bf16* __restrict__ y2out, float* __restrict__ sumA){
  __shared__ __align__(16) bf16 sW[2][64][40];   // [hi/lo][o][k]
  __shared__ __align__(16) bf16 sXT[128][40];    // [l][k]
  __shared__ float f6[6][128];
  __shared__ float w1s[192][6];
  __shared__ float cmv[192], crsv[192], cgv[192];
  int t=threadIdx.x, b=blockIdx.z, o0=blockIdx.y*64, l0=blockIdx.x*128;
  for(int u=t;u<768;u+=256){ int i=u>>7, lc=u&127; f6[i][lc]=b2f(feat[((size_t)(b*6+i))*L0+l0+lc]); }
  for(int u=t;u<1152;u+=256){ w1s[u/6][u%6]=W1[u]; }
  for(int u=t;u<192;u+=256){ int r=b*C0+u; cmv[u]=m1v[r]; crsv[u]=rs1v[r]; cgv[u]=g1v[r]; }
  int wv=t>>6, lane=t&63, nn=lane&15, quad=lane>>4, kb=quad*8;
  int il=t&31, lq=(t>>5)*16;
  f32x4 acc[8];
  #pragma unroll
  for(int i=0;i<8;i++) acc[i]=(f32x4){0.f,0.f,0.f,0.f};
  __syncthreads();
  for(int c=0;c<12;c++){
    int i0=c*32;
    for(int u=t;u<2048;u+=256){
      int oo=u>>5, kk=u&31;
      float w=W2[(size_t)(o0+oo)*384 + i0+kk];
      bf16 hi=f2b(w);
      sW[0][oo][kk]=hi;
      sW[1][oo][kk]=f2b(w-b2f(hi));
    }
    {
      int i=i0+il;
      if(i<192){
        float pv=cgv[i]*rawp[((size_t)(b*C0+i))*M0 + ((l0+lq)>>5)];
        bf16 pb_=f2b(pv);
        #pragma unroll
        for(int u=0;u<16;u++) sXT[lq+u][il]=pb_;
      } else {
        int cc=i-192;
        float w6[6];
        #pragma unroll
        for(int j=0;j<6;j++) w6[j]=w1s[cc][j];
        float mm=cmv[cc], rr=crsv[cc], gg=cgv[cc];
        #pragma unroll
        for(int u=0;u<16;u++){
          float y=0.f;
          #pragma unroll
          for(int j=0;j<6;j++) y=fmaf(w6[j], f6[j][lq+u], y);
          sXT[lq+u][il]=f2b(gg*fmaxf((y-mm)*rr,0.f));
        }
      }
    }
    __syncthreads();
    bf16x8 aHi=*(const bf16x8*)&sW[0][wv*16+nn][kb];
    bf16x8 aLo=*(const bf16x8*)&sW[1][wv*16+nn][kb];
    #pragma unroll
    for(int lt=0;lt<8;lt++){
      bf16x8 bfr_=*(const bf16x8*)&sXT[lt*16+nn][kb];
      acc[lt]=__builtin_amdgcn_mfma_f32_16x16x32_bf16(aHi,bfr_,acc[lt],0,0,0);
      acc[lt]=__builtin_amdgcn_mfma_f32_16x16x32_bf16(aLo,bfr_,acc[lt],0,0,0);
    }
    __syncthreads();
  }
  // store y2 (C/D layout: l=l0+lt*16+nn, o=o0+wv*16+quad*4+r)
  #pragma unroll
  for(int lt=0;lt<8;lt++){
    int l=l0+lt*16+nn;
    #pragma unroll
    for(int r=0;r<4;r++){
      int o=o0+wv*16+quad*4+r;
      y2out[((size_t)(b*C0+o))*L0 + l]=f2b(acc[lt][r]);
    }
  }
  // instance-norm stats: per-o sum/sumsq over this block's 128 l's
  #pragma unroll
  for(int r=0;r<4;r++){
    float s=0.f, s2=0.f;
    #pragma unroll
    for(int lt=0;lt<8;lt++){ float v=acc[lt][r]; s+=v; s2+=v*v; }
    s+=__shfl_down(s,8,64); s2+=__shfl_down(s2,8,64);
    s+=__shfl_down(s,4,64); s2+=__shfl_down(s2,4,64);
    s+=__shfl_down(s,2,64); s2+=__shfl_down(s2,2,64);
    s+=__shfl_down(s,1,64); s2+=__shfl_down(s2,1,64);
    if(nn==0){
      int og=b*C0+o0+wv*16+quad*4+r;
      atomicAdd(&sumA[og],s); atomicAdd(&sumA[768+og],s2);
    }
  }
}

// ---------------- generic MFMA conv (stage-1): Y = (Whi+Wlo)·Xeff ----------------
template<bool CAT>
__global__ __launch_bounds__(256)
void conv_mfma_kernel(const bf16* __restrict__ Whi, const bf16* __restrict__ Wlo,
                      const bf16* __restrict__ X, bf16* __restrict__ Y,
                      int I, int Kpad, int L, int M, size_t xbs, size_t ybs,
                      const float* __restrict__ pmax, const float* __restrict__ g,
                      size_t pbs, size_t gbs, int Cc){
  __shared__ __align__(16) bf16 sW[2][64][40];
  __shared__ __align__(16) bf16 sXT[128][40];
  int t=threadIdx.x, z=blockIdx.z, o0=blockIdx.y*64, l0=blockIdx.x*128;
  const bf16* Xb = X + (size_t)z*xbs;
  bf16* Yb = Y + (size_t)z*ybs;
  const float* pm = CAT ? (pmax + (size_t)z*pbs) : nullptr;
  const float* gz = CAT ? (g + (size_t)z*gbs) : nullptr;
  int wv=t>>6, lane=t&63, nn=lane&15, quad=lane>>4, kb=quad*8;
  int il=t&31, lq=(t>>5)*16;
  f32x4 acc[8];
  #pragma unroll
  for(int i=0;i<8;i++) acc[i]=(f32x4){0.f,0.f,0.f,0.f};
  int nch=Kpad/32;
  for(int c=0;c<nch;c++){
    int i0=c*32;
    for(int u=t;u<2048;u+=256){
      int oo=u>>5, kk=u&31;
      sW[0][oo][kk]=Whi[(size_t)(o0+oo)*Kpad + i0+kk];
      sW[1][oo][kk]=Wlo[(size_t)(o0+oo)*Kpad + i0+kk];
    }
    {
      int i=i0+il;
      if(!CAT){
        if(i<I){
          const bf16* xp = Xb + (size_t)i*L + l0 + lq;
          bf16 tmp[16];
          *(uint4*)&tmp[0]=*(const uint4*)xp;
          *(uint4*)&tmp[8]=*(const uint4*)(xp+8);
          #pragma unroll
          for(int u=0;u<16;u++) sXT[lq+u][il]=tmp[u];
        } else {
          bf16 z0=f2b(0.f);
          #pragma unroll
          for(int u=0;u<16;u++) sXT[lq+u][il]=z0;
        }
      } else {
        if(i<Cc){
          float pv=pm[(size_t)i*M + ((l0+lq)>>5)];
          bf16 pb_=f2b(pv);
          #pragma unroll
          for(int u=0;u<16;u++) sXT[lq+u][il]=pb_;
        } else {
          int ii=i-Cc;
          float gg=gz[ii];
          const bf16* xp = Xb + (size_t)ii*L + l0 + lq;
          bf16 tmp[16];
          *(uint4*)&tmp[0]=*(const uint4*)xp;
          *(uint4*)&tmp[8]=*(const uint4*)(xp+8);
          #pragma unroll
          for(int u=0;u<16;u++) sXT[lq+u][il]=f2b(b2f(tmp[u])*gg);
        }
      }
    }
    __syncthreads();
    bf16x8 aHi=*(const bf16x8*)&sW[0][wv*16+nn][kb];
    bf16x8 aLo=*(const bf16x8*)&sW[1][wv*16+nn][kb];
    #pragma unroll
    for(int lt=0;lt<8;lt++){
      bf16x8 bfr_=*(const bf16x8*)&sXT[lt*16+nn][kb];
      acc[lt]=__builtin_amdgcn_mfma_f32_16x16x32_bf16(aHi,bfr_,acc[lt],0,0,0);
      acc[lt]=__builtin_amdgcn_mfma_f32_16x16x32_bf16(aLo,bfr_,acc[lt],0,0,0);
    }
    __syncthreads();
  }
  #pragma unroll
  for(int lt=0;lt<8;lt++){
    int l=l0+lt*16+nn;
    #pragma unroll
    for(int r=0;r<4;r++){
      int o=o0+wv*16+quad*4+r;
      Yb[(size_t)o*L + l]=f2b(acc[lt][r]);
    }
  }
}

// split f32 weights into hi/lo bf16, zero-padded to Kpad
__global__ __launch_bounds__(256)
void wsplit_kernel(const float* __restrict__ W, bf16* __restrict__ hi, bf16* __restrict__ lo,
                   int I, int Kpad, int n){
  int idx=blockIdx.x*256+threadIdx.x;
  if(idx>=n) return;
  int o=idx/Kpad, k=idx%Kpad;
  float w = (k<I) ? W[(size_t)o*I+k] : 0.f;
  bf16 h=f2b(w);
  hi[idx]=h;
  lo[idx]=f2b(w-b2f(h));
}

// ---------------- stage-0 conv2 VALU (fallback path) ----------------
template<int PB>
__global__ __launch_bounds__(256)
void s0conv2_kernel(const float* __restrict__ W2, const bf16* __restrict__ feat,
                    const float* __restrict__ W1,
                    const float* __restrict__ m1v, const float* __restrict__ rs1v,
                    const float* __restrict__ g1v, const float* __restrict__ rawp,
                    float* __restrict__ sumA,
                    const float* __restrict__ m2v, const float* __restrict__ rs2v,
                    float* __restrict__ ssum2, float* __restrict__ rawm2){
  __shared__ float sW[96][17];
  __shared__ float sX[16][132];
  __shared__ float f6[6][128];
  __shared__ float w1s[192][6];
  __shared__ float cm[192], crs[192], cg[192];
  int t=threadIdx.x, b=blockIdx.z, o0=blockIdx.y*96, l0=blockIdx.x*128;
  for(int u=t;u<768;u+=256){ int i=u>>7, lc=u&127; f6[i][lc]=b2f(feat[((size_t)(b*6+i))*L0+l0+lc]); }
  for(int u=t;u<1152;u+=256){ w1s[u/6][u%6]=W1[u]; }
  for(int u=t;u<192;u+=256){ int r=b*C0+u; cm[u]=m1v[r]; crs[u]=rs1v[r]; cg[u]=g1v[r]; }
  __syncthreads();
  float acc[6][8];
  #pragma unroll
  for(int r=0;r<6;r++)
    #pragma unroll
    for(int c=0;c<8;c++) acc[r][c]=0.f;
  int to=t>>4, tl=t&15, oL=to*6;
  int xr=to, cA=tl*4;
  int mg0=(l0+cA)>>5;
  for(int i0=0;i0<384;i0+=16){
    #pragma unroll
    for(int u=0;u<6;u++){ int flat=u*256+t, r=flat>>4, ci=flat&15;
      sW[r][ci]=W2[(size_t)(o0+r)*384 + i0+ci]; }
    {
      int i=i0+xr;
      float v[8];
      if(i<192){
        float pv0=cg[i]*rawp[((size_t)(b*C0+i))*M0 + mg0];
        float pv1=cg[i]*rawp[((size_t)(b*C0+i))*M0 + mg0+2];
        v[0]=pv0; v[1]=pv0; v[2]=pv0; v[3]=pv0;
        v[4]=pv1; v[5]=pv1; v[6]=pv1; v[7]=pv1;
      } else {
        int c=i-192;
        #pragma unroll
        for(int u=0;u<4;u++){
          float y=0.f;
          #pragma unroll
          for(int j=0;j<6;j++) y=fmaf(w1s[c][j], f6[j][cA+u], y);
          v[u]=cg[c]*fmaxf((y-cm[c])*crs[c],0.f);
        }
        #pragma unroll
        for(int u=0;u<4;u++){
          float y=0.f;
          #pragma unroll
          for(int j=0;j<6;j++) y=fmaf(w1s[c][j], f6[j][64+cA+u], y);
          v[4+u]=cg[c]*fmaxf((y-cm[c])*crs[c],0.f);
        }
      }
      *(float4*)&sX[xr][cA]    = make_float4(v[0],v[1],v[2],v[3]);
      *(float4*)&sX[xr][64+cA] = make_float4(v[4],v[5],v[6],v[7]);
    }
    __syncthreads();
    #pragma unroll
    for(int kk=0;kk<16;kk++){
      float av[6];
      #pragma unroll
      for(int r=0;r<6;r++) av[r]=sW[oL+r][kk];
      float4 xa=*(const float4*)&sX[kk][cA];
      float4 xb=*(const float4*)&sX[kk][64+cA];
      float xv[8]={xa.x,xa.y,xa.z,xa.w,xb.x,xb.y,xb.z,xb.w};
      #pragma unroll
      for(int r=0;r<6;r++)
        #pragma unroll
        for(int c=0;c<8;c++) acc[r][c]=fmaf(av[r],xv[c],acc[r][c]);
    }
    __syncthreads();
  }
  if(PB==0){
    #pragma unroll
    for(int r=0;r<6;r++){
      float ps=0.f, ps2=0.f;
      #pragma unroll
      for(int c=0;c<8;c++){ ps+=acc[r][c]; ps2+=acc[r][c]*acc[r][c]; }
      #pragma unroll
      for(int off=8;off>0;off>>=1){ ps+=__shfl_down(ps,off,64); ps2+=__shfl_down(ps2,off,64); }
      if(tl==0){ int o=b*C0+o0+oL+r; atomicAdd(&sumA[o],ps); atomicAdd(&sumA[768+o],ps2); }
    }
  } else {
    #pragma unroll
    for(int r=0;r<6;r++){
      int o=b*C0+o0+oL+r;
      float mm=m2v[o], rr=rs2v[o];
      float ps=0.f;
      float mxA=-3e38f, mxB=-3e38f;
      #pragma unroll
      for(int c=0;c<4;c++){ float x=fmaxf((acc[r][c]-mm)*rr,0.f); ps+=x; mxA=fmaxf(mxA,x); }
      #pragma unroll
      for(int c=4;c<8;c++){ float x=fmaxf((acc[r][c]-mm)*rr,0.f); ps+=x; mxB=fmaxf(mxB,x); }
      #pragma unroll
      for(int off=8;off>0;off>>=1) ps+=__shfl_down(ps,off,64);
      if(tl==0) atomicAdd(&ssum2[o], ps);
      mxA=fmaxf(mxA,__shfl_down(mxA,4,64)); mxB=fmaxf(mxB,__shfl_down(mxB,4,64));
      mxA=fmaxf(mxA,__shfl_down(mxA,2,64)); mxB=fmaxf(mxB,__shfl_down(mxB,2,64));
      mxA=fmaxf(mxA,__shfl_down(mxA,1,64)); mxB=fmaxf(mxB,__shfl_down(mxB,1,64));
      if(tl==0){ rawm2[(size_t)o*M0 + (l0>>5)    ] = mxA;
                 rawm2[(size_t)o*M0 + (l0>>5) + 2] = mxB; }
      if(tl==8){ rawm2[(size_t)o*M0 + (l0>>5) + 1] = mxA;
                 rawm2[(size_t)o*M0 + (l0>>5) + 3] = mxB; }
    }
  }
}

// ---------------- y2 streaming pool (store path): mean + per-32 max ----------------
__global__ __launch_bounds__(256)
void s0y2_pool_kernel(const bf16* __restrict__ y2, const float* __restrict__ m2v,
                      const float* __restrict__ rs2v,
                      float* __restrict__ rawm2, float* __restrict__ ss02){
  int row=blockIdx.x, t=threadIdx.x;
  const bf16* yr=y2 + (size_t)row*L0;
  float m=m2v[row], rs=rs2v[row];
  float ss=0.f;
  for(int base=t*8;base<L0;base+=2048){
    uint4 r=*(const uint4*)(yr+base);
    float v[8]; unpack8(r,v);
    float mx=-3e38f;
    #pragma unroll
    for(int u=0;u<8;u++){
      float x=fmaxf((v[u]-m)*rs,0.f);
      ss+=x; mx=fmaxf(mx,x);
    }
    mx=fmaxf(mx,__shfl_down(mx,2,64));
    mx=fmaxf(mx,__shfl_down(mx,1,64));
    if((t&3)==0) rawm2[(size_t)row*M0 + (base>>5)] = mx;
  }
  #pragma unroll
  for(int off=32;off>0;off>>=1) ss+=__shfl_down(ss,off,64);
  __shared__ float as[4];
  int w=t>>6;
  if((t&63)==0) as[w]=ss;
  __syncthreads();
  if(t==0) ss02[row]=(as[0]+as[1]+as[2]+as[3])/(float)L0;
}

__global__ __launch_bounds__(256)
void fin_stats_kernel(const float* __restrict__ sums, float invL, int n,
                      float* __restrict__ mp, float* __restrict__ rp){
  int i=blockIdx.x*256+threadIdx.x;
  if(i<n){
    float m=sums[i]*invL;
    float v=sums[n+i]*invL - m*m;
    v=fmaxf(v,0.f);
    mp[i]=m; rp[i]=rsqrtf(v+1e-5f);
  }
}

__global__ __launch_bounds__(256)
void f1fin_kernel(const float* __restrict__ g2, float* __restrict__ rawm,
                  float* __restrict__ outF1){
  int idx=blockIdx.x*256+threadIdx.x;
  int row=idx>>11;
  float v=g2[row]*rawm[idx];
  rawm[idx]=v;
  outF1[idx]=v;
}

// ---------------- stage-1 ----------------
__global__ __launch_bounds__(256)
void feat1_kernel(int bbase, const float* __restrict__ cp1f, const float* __restrict__ cp2f,
                  const float* __restrict__ f1f, const int* __restrict__ idx1,
                  const int* __restrict__ gid1, bf16* __restrict__ featb){
  int t=blockIdx.x*256+threadIdx.x;
  int bloc=t>>14, l=t&16383;
  int b=bbase+bloc;
  int m=l>>5;
  int j=gid1[((size_t)b*M1+m)*32 + (l&31)];
  int sel=idx1[b*M1+m];
  const float* pj=cp1f + ((size_t)b*M0+j)*3;
  const float* cm=cp2f + ((size_t)b*M1+m)*3;
  bf16* fb=featb + (size_t)bloc*195*L1;
  fb[l]       =f2b(pj[0]-cm[0]);
  fb[L1+l]    =f2b(pj[1]-cm[1]);
  fb[2*L1+l]  =f2b(pj[2]-cm[2]);
  const float* fB=f1f + (size_t)b*C0*M0;
  for(int c=0;c<C0;c++)
    fb[(size_t)(3+c)*L1+l]=f2b(fB[(size_t)c*M0+j]-fB[(size_t)c*M0+sel]);
}

template<bool CAT>
__global__ __launch_bounds__(256)
void conv_b_kernel(const float* __restrict__ W, const bf16* __restrict__ X, bf16* __restrict__ Y,
                   int I, int L, int M, size_t xbs, size_t ybs,
                   const float* __restrict__ pmax, const float* __restrict__ g,
                   size_t pbs, size_t gbs, int Cc){
  __shared__ float sX[16][132];
  __shared__ float sW[96][17];
  int t=threadIdx.x, z=blockIdx.z;
  int o0=blockIdx.y*96, l0=blockIdx.x*128;
  const bf16* Xb = X + (size_t)z*xbs;
  bf16* Yb = Y + (size_t)z*ybs;
  const float* pm = CAT ? (pmax + (size_t)z*pbs) : nullptr;
  const float* gz = CAT ? (g + (size_t)z*gbs) : nullptr;
  float acc[6][8];
  #pragma unroll
  for(int r=0;r<6;r++)
    #pragma unroll
    for(int c=0;c<8;c++) acc[r][c]=0.f;
  int to=t>>4, tl=t&15, oL=to*6;
  int xr=to, cA=tl*4;
  int mg0=(l0+cA)>>5;
  for(int i0=0;i0<I;i0+=16){
    #pragma unroll
    for(int u=0;u<6;u++){
      int flat=u*256+t, r=flat>>4, ci=flat&15, i=i0+ci;
      sW[r][ci] = (i<I) ? W[(size_t)(o0+r)*I+i] : 0.f;
    }
    {
      int i=i0+xr;
      float v[8];
      if(!CAT){
        if(i<I){
          const bf16* xp = Xb + (size_t)i*L + l0;
          uint2 ra=*(const uint2*)(xp+cA);
          uint2 rb=*(const uint2*)(xp+64+cA);
          unpack4(ra,v); unpack4(rb,v+4);
        } else {
          #pragma unroll
          for(int u=0;u<8;u++) v[u]=0.f;
        }
      } else {
        if(i<Cc){
          float pv0=pm[(size_t)i*M + mg0];
          float pv1=pm[(size_t)i*M + mg0+2];
          v[0]=pv0; v[1]=pv0; v[2]=pv0; v[3]=pv0;
          v[4]=pv1; v[5]=pv1; v[6]=pv1; v[7]=pv1;
        } else {
          int ii=i-Cc;
          float gg=gz[ii];
          const bf16* xp = Xb + (size_t)ii*L + l0;
          uint2 ra=*(const uint2*)(xp+cA);
          uint2 rb=*(const uint2*)(xp+64+cA);
          unpack4(ra,v); unpack4(rb,v+4);
          #pragma unroll
          for(int u=0;u<8;u++) v[u]*=gg;
        }
      }
      *(float4*)&sX[xr][cA]    = make_float4(v[0],v[1],v[2],v[3]);
      *(float4*)&sX[xr][64+cA] = make_float4(v[4],v[5],v[6],v[7]);
    }
    __syncthreads();
    #pragma unroll
    for(int kk=0;kk<16;kk++){
      float av[6];
      #pragma unroll
      for(int r=0;r<6;r++) av[r]=sW[oL+r][kk];
      float4 xa=*(const float4*)&sX[kk][cA];
      float4 xb=*(const float4*)&sX[kk][64+cA];
      float xv[8]={xa.x,xa.y,xa.z,xa.w,xb.x,xb.y,xb.z,xb.w};
      #pragma unroll
      for(int r=0;r<6;r++)
        #pragma unroll
        for(int c=0;c<8;c++) acc[r][c]=fmaf(av[r],xv[c],acc[r][c]);
    }
    __syncthreads();
  }
  #pragma unroll
  for(int r=0;r<6;r++){
    bf16* yp=Yb + (size_t)(o0+oL+r)*L + l0;
    #pragma unroll
    for(int c=0;c<4;c++) yp[cA+c]=f2b(acc[r][c]);
    #pragma unroll
    for(int c=0;c<4;c++) yp[64+cA+c]=f2b(acc[r][4+c]);
  }
}

__global__ __launch_bounds__(256)
void rowstats_kernel(const bf16* __restrict__ Y, int L,
                     float* __restrict__ meanp, float* __restrict__ rstdp){
  int row=blockIdx.x;
  const uint4* yr=(const uint4*)(Y + (size_t)row*L);
  int nv=L/8;
  float s=0.f, s2=0.f;
  for(int i=threadIdx.x;i<nv;i+=256){
    uint4 r=yr[i]; float v[8]; unpack8(r,v);
    #pragma unroll
    for(int u=0;u<8;u++){ s+=v[u]; s2+=v[u]*v[u]; }
  }
  #pragma unroll
  for(int off=32;off>0;off>>=1){ s+=__shfl_down(s,off,64); s2+=__shfl_down(s2,off,64); }
  __shared__ float as[4], bs[4];
  int w=threadIdx.x>>6;
  if((threadIdx.x&63)==0){ as[w]=s; bs[w]=s2; }
  __syncthreads();
  if(threadIdx.x==0){
    float S=as[0]+as[1]+as[2]+as[3], S2=bs[0]+bs[1]+bs[2]+bs[3];
    float m=S/(float)L, var=S2/(float)L - m*m;
    var=fmaxf(var,0.f);
    meanp[row]=m; rstdp[row]=rsqrtf(var+1e-5f);
  }
}

__global__ __launch_bounds__(256)
void normrelu_kernel(bf16* __restrict__ Y, int L, const float* __restrict__ meanp,
                     const float* __restrict__ rstdp, float* __restrict__ ssum){
  int row=blockIdx.x;
  float m=meanp[row], rs=rstdp[row];
  uint4* yr=(uint4*)(Y + (size_t)row*L);
  int nv=L/8;
  float s=0.f;
  for(int i=threadIdx.x;i<nv;i+=256){
    uint4 r=yr[i]; float v[8]; unpack8(r,v);
    #pragma unroll
    for(int u=0;u<8;u++){ float x=(v[u]-m)*rs; x=fmaxf(x,0.f); v[u]=x; s+=x; }
    uint4 o; o.x=pk2(v[0],v[1]); o.y=pk2(v[2],v[3]); o.z=pk2(v[4],v[5]); o.w=pk2(v[6],v[7]);
    yr[i]=o;
  }
  #pragma unroll
  for(int off=32;off>0;off>>=1) s+=__shfl_down(s,off,64);
  __shared__ float as[4];
  int w=threadIdx.x>>6;
  if((threadIdx.x&63)==0) as[w]=s;
  __syncthreads();
  if(threadIdx.x==0) ssum[row]=(as[0]+as[1]+as[2]+as[3])/(float)L;
}

__global__ __launch_bounds__(256)
void attn_kernel(const float* __restrict__ ssum, const float* __restrict__ w1,
                 const float* __restrict__ w2, int Cc, int H, float* __restrict__ g,
                 float scale){
  __shared__ float sv[384]; __shared__ float hv[96];
  int b=blockIdx.x, t=threadIdx.x;
  for(int i=t;i<Cc;i+=256) sv[i]=ssum[b*Cc+i]*scale;
  __syncthreads();
  if(t<H){
    float a=0.f;
    for(int c=0;c<Cc;c++) a+=w1[(size_t)t*Cc+c]*sv[c];
    hv[t]=fmaxf(a,0.f);
  }
  __syncthreads();
  for(int o=t;o<Cc;o+=256){
    float a=0.f;
    for(int j=0;j<H;j++) a+=w2[(size_t)o*H+j]*hv[j];
    g[b*Cc+o]=1.f/(1.f+expf(-a));
  }
}

__global__ __launch_bounds__(256)
void pmax_kernel(const bf16* __restrict__ Xn, const float* __restrict__ g,
                 int Mloc, float* __restrict__ pm){
  int row=blockIdx.y;
  int m=blockIdx.x*256+threadIdx.x;
  const uint4* x=(const uint4*)(Xn + (size_t)row*Mloc*32 + (size_t)m*32);
  float mv=-3.0e38f;
  #pragma unroll
  for(int i=0;i<4;i++){
    uint4 r=x[i]; float v[8]; unpack8(r,v);
    #pragma unroll
    for(int u=0;u<8;u++) mv=fmaxf(mv,v[u]);
  }
  pm[(size_t)row*Mloc+m]=g[row]*mv;
}

__global__ __launch_bounds__(256)
void fmax_out_kernel(const bf16* __restrict__ Xn, const float* __restrict__ g,
                     int Mloc, float* __restrict__ outp){
  int row=blockIdx.y;
  int m=blockIdx.x*256+threadIdx.x;
  const uint4* x=(const uint4*)(Xn + (size_t)row*Mloc*32 + (size_t)m*32);
  float mv=-3.0e38f;
  #pragma unroll
  for(int i=0;i<4;i++){
    uint4 r=x[i]; float v[8]; unpack8(r,v);
    #pragma unroll
    for(int u=0;u<8;u++) mv=fmaxf(mv,v[u]);
  }
  outp[(size_t)row*Mloc+m]=g[row]*mv;
}

extern "C" void kernel_launch(void* const* d_in, const int* in_sizes, int n_in,
                              void* d_out, int out_size, void* d_ws, size_t ws_size,
                              hipStream_t stream){
  // ---- order-proof input routing by element count ----
  const float* PF[2]={nullptr,nullptr}; int npf=0;
  const float* A9[4]={0,0,0,0};  int n9=0;
  const float* A36[4]={0,0,0,0}; int n36=0;
  const float *s0_w1=0,*s0_w2=0,*s1_w1=0,*s1_w2=0;
  for(int i=0;i<n_in;i++){
    const float* ptr=(const float*)d_in[i];
    switch(in_sizes[i]){
      case 98304:  if(npf<2) PF[npf++]=ptr; break;
      case 1152:   s0_w1=ptr; break;
      case 73728:  s0_w2=ptr; break;
      case 74880:  s1_w1=ptr; break;
      case 294912: s1_w2=ptr; break;
      case 9216:   if(n9<4)  A9[n9++]=ptr;  break;
      case 36864:  if(n36<4) A36[n36++]=ptr; break;
      default: break;
    }
  }
  const float* s0_a1w1=A9[0];  const float* s0_a1w2=A9[1];
  const float* s0_a2w1=A9[2];  const float* s0_a2w2=A9[3];
  const float* s1_a1w1=A36[0]; const float* s1_a1w2=A36[1];
  const float* s1_a2w1=A36[2]; const float* s1_a2w2=A36[3];

  float* out=(float*)d_out;
  char* ws=(char*)d_ws;

  int*   flag =(int*)  (ws+A_FLAG);
  float* cp1f =(float*)(ws+A_CP1F);
  float* cp2f =(float*)(ws+A_CP2F);
  int*   idx0 =(int*)  (ws+A_IDX0);
  int*   idx1 =(int*)  (ws+A_IDX1);
  int*   gid0 =(int*)  (ws+A_GID0);
  int*   gid1 =(int*)  (ws+A_GID1);
  bf16*  feat0=(bf16*) (ws+A_FEAT0);
  float* m1v  =(float*)(ws+A_M1V);
  float* rs1v =(float*)(ws+A_RS1V);
  float* ss01 =(float*)(ws+A_SS01);
  float* g1v  =(float*)(ws+A_G1V);
  float* sumA =(float*)(ws+A_SUMA);
  float* ss02 =(float*)(ws+A_SS02);
  float* m2v  =(float*)(ws+A_M2V);
  float* rs2v =(float*)(ws+A_RS2V);
  float* g2v  =(float*)(ws+A_G2V);
  float* rawp =(float*)(ws+A_RAWP);
  float* rawm2=(float*)(ws+A_RAWM2);
  float* f1f  =rawm2;
  bf16*  y2s0 =(bf16*) (ws+A_Y2);

  detect_kernel<<<1,64,0,stream>>>(PF[0], flag);
  cvt_pf_kernel<<<384,256,0,stream>>>(PF[0], PF[1], flag, out+OUT_P, out+OUT_F, B_*N0*3);

  // ---- stage 0: sampling/grouping (fps epilogue does the centroid gather) ----
  fps_kernel<N0,M0,256><<<B_,256,0,stream>>>(PF[0], PF[1], flag, idx0, cp1f, out+OUT_CP1);
  ballq_kernel<N0,M0><<<dim3(32,B_),256,0,stream>>>(PF[0], PF[1], flag, cp1f, gid0);
  feat0_kernel<<<1024,256,0,stream>>>(PF[0], PF[1], flag, cp1f, idx0, gid0, feat0);

  // ---- stage 0: conv block 1 (virtual) ----
  s0c1_stats_kernel<<<B_*C0,256,0,stream>>>(feat0, s0_w1, m1v, rs1v);
  s0c1_pool_kernel<<<B_*C0,256,0,stream>>>(feat0, s0_w1, m1v, rs1v, rawp, ss01);
  attn_kernel<<<B_,256,0,stream>>>(ss01, s0_a1w1, s0_a1w2, C0, H0, g1v, 1.f);

  // ---- stage 0: conv block 2 ----
  if(ws_size >= WS_Y2){
    hipMemsetAsync(ws+A_SUMA, 0, 6144, stream);
    s0conv2_mfma_kernel<<<dim3(512,3,B_),256,0,stream>>>(s0_w2, feat0, s0_w1, m1v, rs1v, g1v, rawp, y2s0, sumA);
    fin_stats_kernel<<<3,256,0,stream>>>(sumA, 1.f/(float)L0, 768, m2v, rs2v);
    s0y2_pool_kernel<<<B_*C0,256,0,stream>>>(y2s0, m2v, rs2v, rawm2, ss02);
    attn_kernel<<<B_,256,0,stream>>>(ss02, s0_a2w1, s0_a2w2, C0, H0, g2v, 1.f);
  } else {
    hipMemsetAsync(ws+A_SUMA, 0, 9216, stream);
    s0conv2_kernel<0><<<dim3(512,2,B_),256,0,stream>>>(s0_w2, feat0, s0_w1, m1v, rs1v, g1v,
                                                       rawp, sumA, nullptr,nullptr,nullptr,nullptr);
    fin_stats_kernel<<<3,256,0,stream>>>(sumA, 1.f/(float)L0, 768, m2v, rs2v);
    s0conv2_kernel<1><<<dim3(512,2,B_),256,0,stream>>>(s0_w2, feat0, s0_w1, m1v, rs1v, g1v,
                                                       rawp, nullptr, m2v, rs2v, ss02, rawm2);
    attn_kernel<<<B_,256,0,stream>>>(ss02, s0_a2w1, s0_a2w2, C0, H0, g2v, 1.f/(float)L0);
  }
  f1fin_kernel<<<6144,256,0,stream>>>(g2v, rawm2, out+OUT_F1);

  // ---- stage 1: sampling/grouping ----
  fps_kernel<M0,M1,256><<<B_,256,0,stream>>>(cp1f, cp1f, nullptr, idx1, cp2f, out+OUT_CP2);
  ballq_kernel<M0,M1><<<dim3(8,B_),256,0,stream>>>(cp1f, cp1f, nullptr, cp2f, gid1);

  if(ws_size >= A_NEED){
    // ---- batch-parallel stage 1 ----
    bf16*  f1a =(bf16*) (ws+A_F1A);
    bf16*  yb1a=(bf16*) (ws+A_YB1A);
    bf16*  yb2a=(bf16*) (ws+A_YB2A);
    float* pma =(float*)(ws+A_PMA);
    float* msa =(float*)(ws+A_MSA);
    float* rsa =(float*)(ws+A_RSA);
    float* ssa =(float*)(ws+A_SSA);
    float* g1a =(float*)(ws+A_G1A);
    float* g2a =(float*)(ws+A_G2A);
    bool mfma1 = (ws_size >= A_NEED2);
    bf16* w1h=(bf16*)(ws+A_W1H); bf16* w1l=(bf16*)(ws+A_W1L);
    bf16* w2h=(bf16*)(ws+A_W2H); bf16* w2l=(bf16*)(ws+A_W2L);
    if(mfma1){
      wsplit_kernel<<<(384*224+255)/256,256,0,stream>>>(s1_w1, w1h, w1l, 195, 224, 384*224);
      wsplit_kernel<<<(384*768+255)/256,256,0,stream>>>(s1_w2, w2h, w2l, 768, 768, 384*768);
    }
    feat1_kernel<<<B_*L1/256,256,0,stream>>>(0, cp1f, cp2f, f1f, idx1, gid1, f1a);
    if(mfma1)
      conv_mfma_kernel<false><<<dim3(L1/128,C1/64,B_),256,0,stream>>>(w1h, w1l, f1a, yb1a,
                                 195, 224, L1, M1, (size_t)195*L1, (size_t)C1*L1,
                                 nullptr,nullptr,0,0,0);
    else
      conv_b_kernel<false><<<dim3(L1/128,4,B_),256,0,stream>>>(s1_w1, f1a, yb1a, 195, L1, M1,
                                 (size_t)195*L1, (size_t)C1*L1, nullptr,nullptr,0,0,0);
    rowstats_kernel<<<B_*C1,256,0,stream>>>(yb1a, L1, msa, rsa);
    normrelu_kernel<<<B_*C1,256,0,stream>>>(yb1a, L1, msa, rsa, ssa);
    attn_kernel<<<B_,256,0,stream>>>(ssa, s1_a1w1, s1_a1w2, C1, H1, g1a, 1.f);
    pmax_kernel<<<dim3(2,B_*C1),256,0,stream>>>(yb1a, g1a, M1, pma);
    if(mfma1)
      conv_mfma_kernel<true><<<dim3(L1/128,C1/64,B_),256,0,stream>>>(w2h, w2l, yb1a, yb2a,
                                 768, 768, L1, M1, (size_t)C1*L1, (size_t)C1*L1,
                                 pma, g1a, (size_t)C1*M1, (size_t)C1, C1);
    else
      conv_b_kernel<true><<<dim3(L1/128,4,B_),256,0,stream>>>(s1_w2, yb1a, yb2a, 2*C1, L1, M1,
                                 (size_t)C1*L1, (size_t)C1*L1, pma, g1a, (size_t)C1*M1, (size_t)C1, C1);
    rowstats_kernel<<<B_*C1,256,0,stream>>>(yb2a, L1, msa, rsa);
    normrelu_kernel<<<B_*C1,256,0,stream>>>(yb2a, L1, msa, rsa, ssa);
    attn_kernel<<<B_,256,0,stream>>>(ssa, s1_a2w1, s1_a2w2, C1, H1, g2a, 1.f);
    fmax_out_kernel<<<dim3(2,B_*C1),256,0,stream>>>(yb2a, g2a, M1, out+OUT_F2);
  } else {
    // ---- serial fallback ----
    bf16*  feat1b=(bf16*)(ws+A_FEAT1);
    bf16*  ybuf1 =(bf16*)(ws+A_YB1);
    bf16*  ybuf2 =(bf16*)(ws+A_YB2);
    float* pmS1 =(float*)(ws+A_PMS1);
    float* mS1  =(float*)(ws+A_MS1);
    float* rsS1 =(float*)(ws+A_RSS1);
    float* ssS1 =(float*)(ws+A_SSS1);
    float* g1s1 =(float*)(ws+A_G1S1);
    float* g2s1 =(float*)(ws+A_G2S1);
    for(int b=0;b<B_;b++){
      feat1_kernel<<<64,256,0,stream>>>(b, cp1f, cp2f, f1f, idx1, gid1, feat1b);
      conv_b_kernel<false><<<dim3(L1/128,4,1),256,0,stream>>>(s1_w1, feat1b, ybuf1, 195, L1, M1,
                                   0,0, nullptr,nullptr,0,0,0);
      rowstats_kernel<<<C1,256,0,stream>>>(ybuf1, L1, mS1, rsS1);
      normrelu_kernel<<<C1,256,0,stream>>>(ybuf1, L1, mS1, rsS1, ssS1);
      attn_kernel<<<1,256,0,stream>>>(ssS1, s1_a1w1, s1_a1w2, C1, H1, g1s1, 1.f);
      pmax_kernel<<<dim3(2,C1),256,0,stream>>>(ybuf1, g1s1, M1, pmS1);
      conv_b_kernel<true><<<dim3(L1/128,4,1),256,0,stream>>>(s1_w2, ybuf1, ybuf2, 2*C1, L1, M1,
                                   0,0, pmS1, g1s1, 0,0, C1);
      rowstats_kernel<<<C1,256,0,stream>>>(ybuf2, L1, mS1, rsS1);
      normrelu_kernel<<<C1,256,0,stream>>>(ybuf2, L1, mS1, rsS1, ssS1);
      attn_kernel<<<1,256,0,stream>>>(ssS1, s1_a2w1, s1_a2w2, C1, H1, g2s1, 1.f);
      fmax_out_kernel<<<dim3(2,C1),256,0,stream>>>(ybuf2, g2s1, M1, out+OUT_F2+(size_t)b*C1*M1);
    }
  }
}